// Round 1
// baseline (7621.328 us; speedup 1.0000x reference)
//
#include <hip/hip_runtime.h>
#include <cstddef>

#define TIME_N 262144
#define BATCH  32
#define KW     1024
#define ST     256
#define CUTN   513
#define TCN    1026
#define TCP    1028   // padded row stride for t (16B-aligned rows)
#define FN     1029   // frames

// ---------------------------------------------------------------------------
// Kernel 1: conv1 (stride 256, pad 1024) fused with tanh(gamma * .)
// t[b][f][c] = tanh(gamma[c] * sum_k x[b, f*256 + k - 1024] * w[c][k])
// Block: 32 frames x 64 channels; 256 threads = 32 cgroups x 8 fgroups.
// Each thread: 2 channels x 4 frames.
// ---------------------------------------------------------------------------
__global__ __launch_bounds__(256) void k_conv1(
    const float* __restrict__ x, const float* __restrict__ w,
    const float* __restrict__ gamma, float* __restrict__ t)
{
    __shared__ __align__(16) float win[8960];   // (32-1)*256 + 1024
    const int fb = blockIdx.x;      // 0..32
    const int cb = blockIdx.y;      // 0..16
    const int b  = blockIdx.z;      // 0..31
    const int f0 = fb * 32;
    const int w0 = f0 * ST - KW;
    const float* xb = x + (size_t)b * TIME_N;
    for (int idx = threadIdx.x; idx < 8960; idx += 256) {
        int g = w0 + idx;
        win[idx] = (g >= 0 && g < TIME_N) ? xb[g] : 0.0f;
    }
    __syncthreads();

    const int cg = threadIdx.x & 31;
    const int fg = threadIdx.x >> 5;       // 0..7
    const int c0 = cb * 64 + cg;
    const int c1 = c0 + 32;
    const int c0s = (c0 < TCN) ? c0 : (TCN - 1);
    const int c1s = (c1 < TCN) ? c1 : (TCN - 1);
    const float4* wa = (const float4*)(w + (size_t)c0s * KW);
    const float4* wb = (const float4*)(w + (size_t)c1s * KW);

    float acc0[4] = {0.f, 0.f, 0.f, 0.f};
    float acc1[4] = {0.f, 0.f, 0.f, 0.f};

    for (int k4 = 0; k4 < KW / 4; ++k4) {
        const float4 u = wa[k4];
        const float4 v = wb[k4];
        const int kb = k4 * 4;
#pragma unroll
        for (int jj = 0; jj < 4; ++jj) {
            const float4 xv = *(const float4*)&win[(fg + 8 * jj) * ST + kb];
            acc0[jj] += u.x * xv.x + u.y * xv.y + u.z * xv.z + u.w * xv.w;
            acc1[jj] += v.x * xv.x + v.y * xv.y + v.z * xv.z + v.w * xv.w;
        }
    }

    const float g0 = gamma[c0s];
    const float g1 = gamma[c1s];
#pragma unroll
    for (int jj = 0; jj < 4; ++jj) {
        const int f = f0 + fg + 8 * jj;
        if (f < FN) {
            float* row = t + ((size_t)b * FN + f) * TCP;
            if (c0 < TCN) {
                float u0 = acc0[jj] * g0;
                row[c0] = 2.0f / (1.0f + __expf(-2.0f * u0)) - 1.0f;
            }
            if (c1 < TCN) {
                float u1 = acc1[jj] * g1;
                row[c1] = 2.0f / (1.0f + __expf(-2.0f * u1)) - 1.0f;
            }
        }
    }
}

// ---------------------------------------------------------------------------
// Kernel 2: fused comb1/comb2 -> h, linear(513x513) -> mask = sigma(2v),
// then in-place t *= mask (both halves). One block = (b, 8 frames).
// ---------------------------------------------------------------------------
__global__ __launch_bounds__(256) void k_mask(
    float* __restrict__ t,
    const float* __restrict__ c1w, const float* __restrict__ c1b,
    const float* __restrict__ c2w, const float* __restrict__ c2b,
    const float* __restrict__ lin_w, const float* __restrict__ lin_b,
    const float* __restrict__ fcg)
{
    __shared__ __align__(16) float h[8 * CUTN];   // 4104 floats
    const int ft = blockIdx.x;   // 0..128
    const int b  = blockIdx.y;
    const int f0 = ft * 8;

    float w1[16], b1[8], w2[8];
#pragma unroll
    for (int o = 0; o < 8; ++o) {
        w1[2 * o]     = c1w[2 * o];
        w1[2 * o + 1] = c1w[2 * o + 1];
        b1[o] = c1b[o];
        w2[o] = c2w[o];
    }
    const float b2v = c2b[0];

    // stage h[f_local][x] for 8 frames
    for (int idx = threadIdx.x; idx < 8 * CUTN; idx += 256) {
        const int fl = idx / CUTN;
        const int xx = idx - fl * CUTN;
        const int f  = f0 + fl;
        float hv = 0.0f;
        if (f < FN) {
            const float* row = t + ((size_t)b * FN + f) * TCP;
            const float re = row[xx];
            const float im = row[xx + CUTN];
            float a2 = b2v;
#pragma unroll
            for (int o = 0; o < 8; ++o) {
                float a1 = fmaxf(re * w1[2 * o] + im * w1[2 * o + 1] + b1[o], 0.0f);
                a2 += a1 * w2[o];
            }
            hv = fmaxf(a2, 0.0f);
        }
        h[idx] = hv;
    }
    __syncthreads();

    // linear: out[f][x'] = sum_y h[f][y] * lin_w[x'][y]
    const int xg = threadIdx.x & 127;   // 128 x-groups of 4
    const int fg = threadIdx.x >> 7;    // 2 f-groups of 4 frames
    const int x0 = xg * 4;

    float acc[4][4];
#pragma unroll
    for (int q = 0; q < 4; ++q)
#pragma unroll
        for (int ff = 0; ff < 4; ++ff) acc[q][ff] = 0.0f;

    const float* wr = lin_w + (size_t)x0 * CUTN;
    for (int y = 0; y < CUTN; ++y) {
        const float wv0 = wr[y];
        const float wv1 = wr[CUTN + y];
        const float wv2 = wr[2 * CUTN + y];
        const float wv3 = wr[3 * CUTN + y];
#pragma unroll
        for (int ff = 0; ff < 4; ++ff) {
            const float hv = h[(fg * 4 + ff) * CUTN + y];
            acc[0][ff] += wv0 * hv;
            acc[1][ff] += wv1 * hv;
            acc[2][ff] += wv2 * hv;
            acc[3][ff] += wv3 * hv;
        }
    }

#pragma unroll
    for (int q = 0; q < 4; ++q) {
        const int xx = x0 + q;
        const float lb = lin_b[xx];
        const float fgam = fcg[xx];
#pragma unroll
        for (int ff = 0; ff < 4; ++ff) {
            const int f = f0 + fg * 4 + ff;
            if (f < FN) {
                const float v = (acc[q][ff] + lb) * fgam;
                const float m = 1.0f / (1.0f + __expf(-2.0f * v));  // (tanh(v)+1)/2
                float* row = t + ((size_t)b * FN + f) * TCP;
                row[xx]        *= m;
                row[xx + CUTN] *= m;
            }
        }
    }

    // tail: x' = 512
    if (threadIdx.x < 8) {
        const int f = f0 + threadIdx.x;
        if (f < FN) {
            const float* wr2 = lin_w + (size_t)512 * CUTN;
            const float* hr  = h + threadIdx.x * CUTN;
            float a0 = 0.f, a1 = 0.f, a2 = 0.f, a3 = 0.f;
            int y = 0;
            for (; y + 4 <= CUTN; y += 4) {
                a0 += wr2[y]     * hr[y];
                a1 += wr2[y + 1] * hr[y + 1];
                a2 += wr2[y + 2] * hr[y + 2];
                a3 += wr2[y + 3] * hr[y + 3];
            }
            for (; y < CUTN; ++y) a0 += wr2[y] * hr[y];
            const float v = (a0 + a1 + a2 + a3 + lin_b[512]) * fcg[512];
            const float m = 1.0f / (1.0f + __expf(-2.0f * v));
            float* row = t + ((size_t)b * FN + f) * TCP;
            row[512]        *= m;
            row[512 + CUTN] *= m;
        }
    }
}

// ---------------------------------------------------------------------------
// Prep: differenced transposed-conv weights.
// Wd[(j*1026+i)*256 + r] = W[i,0,(3-j)*256+r] - W[i,1,(3-j)*256+r]
// ---------------------------------------------------------------------------
__global__ __launch_bounds__(256) void k_wdiff(
    const float* __restrict__ wct, float* __restrict__ wd)
{
    const int i = blockIdx.x;    // 0..1025
    const int j = blockIdx.y;    // 0..3
    const int r = threadIdx.x;   // 0..255
    const int widx = (3 - j) * 256 + r;
    wd[((size_t)(j * TCN + i)) * 256 + r] =
        wct[((size_t)(i * 2)) * KW + widx] - wct[((size_t)(i * 2 + 1)) * KW + widx];
}

// ---------------------------------------------------------------------------
// Kernel 3: transposed conv as GEMV-per-(b,m) with differenced weights,
// fused softmax. d[r] = sum_{j,i} t[b][m+1+j][i] * Wd[j*1026+i][r]
// Block: 8 m x 256 r, K split over 4 waves (j = wave id).
// ---------------------------------------------------------------------------
__global__ __launch_bounds__(256) void k_convt(
    const float* __restrict__ t, const float* __restrict__ wd,
    float* __restrict__ out)
{
    __shared__ __align__(16) float a[11 * TCN];   // 11286 floats
    __shared__ float red[1024];
    const int mt = blockIdx.x;   // 0..127
    const int b  = blockIdx.y;
    const int m0 = mt * 8;

    const float* tb = t + ((size_t)b * FN + m0 + 1) * TCP;
    for (int fr = 0; fr < 11; ++fr)
        for (int i = threadIdx.x; i < TCN; i += 256)
            a[fr * TCN + i] = tb[(size_t)fr * TCP + i];
    __syncthreads();

    const int rg = threadIdx.x & 63;   // 64 r-groups of 4 (float4)
    const int kg = threadIdx.x >> 6;   // wave id == j

    float acc[4][8];
#pragma unroll
    for (int q = 0; q < 4; ++q)
#pragma unroll
        for (int mm = 0; mm < 8; ++mm) acc[q][mm] = 0.0f;

    const float4* wp = (const float4*)wd + (size_t)(kg * TCN) * 64 + rg;
    const float*  ar = a + kg * TCN;

    for (int i = 0; i < TCN; ++i) {
        const float4 wv = wp[(size_t)i * 64];
#pragma unroll
        for (int mm = 0; mm < 8; ++mm) {
            const float av = ar[mm * TCN + i];   // wave-uniform broadcast
            acc[0][mm] += wv.x * av;
            acc[1][mm] += wv.y * av;
            acc[2][mm] += wv.z * av;
            acc[3][mm] += wv.w * av;
        }
    }

    float* ob = out + (size_t)b * 2 * TIME_N;
#pragma unroll 1
    for (int mm = 0; mm < 8; ++mm) {
        __syncthreads();
        red[kg * 256 + rg * 4 + 0] = acc[0][mm];
        red[kg * 256 + rg * 4 + 1] = acc[1][mm];
        red[kg * 256 + rg * 4 + 2] = acc[2][mm];
        red[kg * 256 + rg * 4 + 3] = acc[3][mm];
        __syncthreads();
        const float d = red[threadIdx.x] + red[256 + threadIdx.x] +
                        red[512 + threadIdx.x] + red[768 + threadIdx.x];
        const float p0 = 1.0f / (1.0f + __expf(-d));
        const int tau = (m0 + mm) * 256 + threadIdx.x;
        ob[tau]          = p0;
        ob[TIME_N + tau] = 1.0f - p0;
    }
}

extern "C" void kernel_launch(void* const* d_in, const int* in_sizes, int n_in,
                              void* d_out, int out_size, void* d_ws, size_t ws_size,
                              hipStream_t stream)
{
    const float* x    = (const float*)d_in[0];
    const float* c1w  = (const float*)d_in[1];
    const float* ing  = (const float*)d_in[2];
    const float* cb1w = (const float*)d_in[3];
    const float* cb1b = (const float*)d_in[4];
    const float* cb2w = (const float*)d_in[5];
    const float* cb2b = (const float*)d_in[6];
    const float* linw = (const float*)d_in[7];
    const float* linb = (const float*)d_in[8];
    const float* fcg  = (const float*)d_in[9];
    const float* ctw  = (const float*)d_in[10];
    float* out = (float*)d_out;

    float* t  = (float*)d_ws;                          // 32*1029*1028 floats
    float* wd = t + (size_t)BATCH * FN * TCP;          // 4104*256 floats

    hipLaunchKernelGGL(k_wdiff, dim3(TCN, 4), dim3(256), 0, stream, ctw, wd);
    hipLaunchKernelGGL(k_conv1, dim3(33, 17, BATCH), dim3(256), 0, stream,
                       x, c1w, ing, t);
    hipLaunchKernelGGL(k_mask, dim3(129, BATCH), dim3(256), 0, stream,
                       t, cb1w, cb1b, cb2w, cb2b, linw, linb, fcg);
    hipLaunchKernelGGL(k_convt, dim3(128, BATCH), dim3(256), 0, stream,
                       t, wd, out);
}

// Round 2
// 3996.511 us; speedup vs baseline: 1.9070x; 1.9070x over previous
//
#include <hip/hip_runtime.h>
#include <cstddef>
#include <cstdint>

#define TIME_N 262144
#define BATCH  32
#define KW     1024
#define ST     256
#define CUTN   513
#define TCN    1026
#define TCP    1028   // padded row stride for t (16B-aligned rows)
#define FN     1029   // frames
#define FPAD   1152   // padded frames (9*128)
#define CPAD   1152   // padded channels (9*128)
#define XLEN   (FPAD * ST + KW)   // 295936 padded x row (bf16), covers f<1152 windows

typedef unsigned int uint;
typedef unsigned short ushort_t;
typedef __bf16 bf16x8 __attribute__((ext_vector_type(8)));
typedef float floatx4 __attribute__((ext_vector_type(4)));

__device__ __forceinline__ unsigned short f2bf(float f) {
    union { float f; unsigned u; } v; v.f = f;
    unsigned r = (v.u + 0x7fffu + ((v.u >> 16) & 1u)) >> 16;
    return (unsigned short)r;
}

__device__ __forceinline__ void load_lds16(const void* g, void* l) {
    __builtin_amdgcn_global_load_lds(
        (const __attribute__((address_space(1))) void*)g,
        (__attribute__((address_space(3))) void*)l, 16, 0, 0);
}

// ---------------------------------------------------------------------------
// Prep A: zero-padded bf16 copy of x. xb[b][p] = x[b][p-1024] (0 outside).
// Window for frame f is xb[b][f*256 .. f*256+1024).
// ---------------------------------------------------------------------------
__global__ __launch_bounds__(256) void k_xpad(
    const float* __restrict__ x, unsigned short* __restrict__ xb)
{
    const int p = blockIdx.x * 256 + threadIdx.x;   // 0..XLEN-1 (grid.x = 1156)
    const int b = blockIdx.y;
    const int g = p - KW;
    float v = (g >= 0 && g < TIME_N) ? x[(size_t)b * TIME_N + g] : 0.0f;
    xb[(size_t)b * XLEN + p] = f2bf(v);
}

// ---------------------------------------------------------------------------
// Prep B: bf16 weights padded to [1152][1024] (zero rows for c >= 1026).
// ---------------------------------------------------------------------------
__global__ __launch_bounds__(256) void k_wbf(
    const float* __restrict__ w, unsigned short* __restrict__ wb)
{
    const int c = blockIdx.x;   // 0..1151
    for (int k = threadIdx.x; k < KW; k += 256) {
        float v = (c < TCN) ? w[(size_t)c * KW + k] : 0.0f;
        wb[(size_t)c * KW + k] = f2bf(v);
    }
}

// ---------------------------------------------------------------------------
// Kernel 1 (MFMA): conv1 as bf16 GEMM, tanh(gamma*.) fused epilogue.
// C[f,c] = sum_k xb[b][f*256+k] * wb[c][k];  128x128 tile, BK=32, m97 recipe.
// 256 threads = 4 waves in 2x2; each wave: 64x64 = 4x4 MFMA 16x16x32 tiles.
// ---------------------------------------------------------------------------
__global__ __launch_bounds__(256) void k_conv1m(
    const unsigned short* __restrict__ xb, const unsigned short* __restrict__ wb,
    const float* __restrict__ gamma, float* __restrict__ t)
{
    __shared__ __align__(16) unsigned short As[128 * 32];
    __shared__ __align__(16) unsigned short Bs[128 * 32];

    const int fb = blockIdx.x;   // 0..8
    const int cb = blockIdx.y;   // 0..8
    const int b  = blockIdx.z;
    const int f0 = fb * 128;
    const int c0 = cb * 128;
    const int tid = threadIdx.x;

    // --- staging addresses: segment s in [0,512), row=s>>2, quad=s&3 ---
    const int s0 = tid, s1 = tid + 256;
    const int ar0 = s0 >> 2, aq0 = s0 & 3;
    const int ar1 = s1 >> 2, aq1 = s1 & 3;
    const unsigned short* xrow = xb + (size_t)b * XLEN;
    const unsigned short* ga0 = xrow + (size_t)(f0 + ar0) * ST + aq0 * 8;
    const unsigned short* ga1 = xrow + (size_t)(f0 + ar1) * ST + aq1 * 8;
    const unsigned short* gb0 = wb + (size_t)(c0 + ar0) * KW + aq0 * 8;
    const unsigned short* gb1 = wb + (size_t)(c0 + ar1) * KW + aq1 * 8;
    unsigned short* la0 = &As[s0 * 8];
    unsigned short* la1 = &As[s1 * 8];
    unsigned short* lb0 = &Bs[s0 * 8];
    unsigned short* lb1 = &Bs[s1 * 8];

    // --- fragment addresses ---
    const int wave = tid >> 6, lane = tid & 63;
    const int lm = lane & 15, lq = lane >> 4;
    const int mw = (wave & 1) * 64, nw = (wave >> 1) * 64;
    const unsigned short* Ap = &As[(mw + lm) * 32 + lq * 8];
    const unsigned short* Bp = &Bs[(nw + lm) * 32 + lq * 8];

    floatx4 acc[4][4];
#pragma unroll
    for (int i = 0; i < 4; ++i)
#pragma unroll
        for (int j = 0; j < 4; ++j) acc[i][j] = (floatx4)0.0f;

    for (int ks = 0; ks < KW / 32; ++ks) {
        load_lds16(ga0, la0);
        load_lds16(ga1, la1);
        load_lds16(gb0, lb0);
        load_lds16(gb1, lb1);
        ga0 += 32; ga1 += 32; gb0 += 32; gb1 += 32;
        __syncthreads();

        bf16x8 afr[4], bfr[4];
#pragma unroll
        for (int mt = 0; mt < 4; ++mt) afr[mt] = *(const bf16x8*)(Ap + mt * 16 * 32);
#pragma unroll
        for (int nt = 0; nt < 4; ++nt) bfr[nt] = *(const bf16x8*)(Bp + nt * 16 * 32);
#pragma unroll
        for (int mt = 0; mt < 4; ++mt)
#pragma unroll
            for (int nt = 0; nt < 4; ++nt)
                acc[mt][nt] = __builtin_amdgcn_mfma_f32_16x16x32_bf16(
                    afr[mt], bfr[nt], acc[mt][nt], 0, 0, 0);
        __syncthreads();
    }

    // --- epilogue: D[row=lq*4+r][col=lm], tanh(gamma*v) -> t[b][f][c] ---
#pragma unroll
    for (int nt = 0; nt < 4; ++nt) {
        const int c = c0 + nw + nt * 16 + lm;
        if (c < TCN) {
            const float gv = gamma[c];
#pragma unroll
            for (int mt = 0; mt < 4; ++mt) {
#pragma unroll
                for (int r = 0; r < 4; ++r) {
                    const int f = f0 + mw + mt * 16 + lq * 4 + r;
                    if (f < FN) {
                        const float u = acc[mt][nt][r] * gv;
                        t[((size_t)b * FN + f) * TCP + c] =
                            2.0f / (1.0f + __expf(-2.0f * u)) - 1.0f;
                    }
                }
            }
        }
    }
}

// ---------------------------------------------------------------------------
// Kernel 2: fused comb1/comb2 -> h, linear(513x513) -> mask = sigma(2v),
// then in-place t *= mask (both halves). One block = (b, 8 frames).
// ---------------------------------------------------------------------------
__global__ __launch_bounds__(256) void k_mask(
    float* __restrict__ t,
    const float* __restrict__ c1w, const float* __restrict__ c1b,
    const float* __restrict__ c2w, const float* __restrict__ c2b,
    const float* __restrict__ lin_w, const float* __restrict__ lin_b,
    const float* __restrict__ fcg)
{
    __shared__ __align__(16) float h[8 * CUTN];   // 4104 floats
    const int ft = blockIdx.x;   // 0..128
    const int b  = blockIdx.y;
    const int f0 = ft * 8;

    float w1[16], b1[8], w2[8];
#pragma unroll
    for (int o = 0; o < 8; ++o) {
        w1[2 * o]     = c1w[2 * o];
        w1[2 * o + 1] = c1w[2 * o + 1];
        b1[o] = c1b[o];
        w2[o] = c2w[o];
    }
    const float b2v = c2b[0];

    for (int idx = threadIdx.x; idx < 8 * CUTN; idx += 256) {
        const int fl = idx / CUTN;
        const int xx = idx - fl * CUTN;
        const int f  = f0 + fl;
        float hv = 0.0f;
        if (f < FN) {
            const float* row = t + ((size_t)b * FN + f) * TCP;
            const float re = row[xx];
            const float im = row[xx + CUTN];
            float a2 = b2v;
#pragma unroll
            for (int o = 0; o < 8; ++o) {
                float a1 = fmaxf(re * w1[2 * o] + im * w1[2 * o + 1] + b1[o], 0.0f);
                a2 += a1 * w2[o];
            }
            hv = fmaxf(a2, 0.0f);
        }
        h[idx] = hv;
    }
    __syncthreads();

    const int xg = threadIdx.x & 127;
    const int fg = threadIdx.x >> 7;
    const int x0 = xg * 4;

    float acc[4][4];
#pragma unroll
    for (int q = 0; q < 4; ++q)
#pragma unroll
        for (int ff = 0; ff < 4; ++ff) acc[q][ff] = 0.0f;

    const float* wr = lin_w + (size_t)x0 * CUTN;
    for (int y = 0; y < CUTN; ++y) {
        const float wv0 = wr[y];
        const float wv1 = wr[CUTN + y];
        const float wv2 = wr[2 * CUTN + y];
        const float wv3 = wr[3 * CUTN + y];
#pragma unroll
        for (int ff = 0; ff < 4; ++ff) {
            const float hv = h[(fg * 4 + ff) * CUTN + y];
            acc[0][ff] += wv0 * hv;
            acc[1][ff] += wv1 * hv;
            acc[2][ff] += wv2 * hv;
            acc[3][ff] += wv3 * hv;
        }
    }

#pragma unroll
    for (int q = 0; q < 4; ++q) {
        const int xx = x0 + q;
        const float lb = lin_b[xx];
        const float fgam = fcg[xx];
#pragma unroll
        for (int ff = 0; ff < 4; ++ff) {
            const int f = f0 + fg * 4 + ff;
            if (f < FN) {
                const float v = (acc[q][ff] + lb) * fgam;
                const float m = 1.0f / (1.0f + __expf(-2.0f * v));
                float* row = t + ((size_t)b * FN + f) * TCP;
                row[xx]        *= m;
                row[xx + CUTN] *= m;
            }
        }
    }

    if (threadIdx.x < 8) {
        const int f = f0 + threadIdx.x;
        if (f < FN) {
            const float* wr2 = lin_w + (size_t)512 * CUTN;
            const float* hr  = h + threadIdx.x * CUTN;
            float a0 = 0.f, a1 = 0.f, a2 = 0.f, a3 = 0.f;
            int y = 0;
            for (; y + 4 <= CUTN; y += 4) {
                a0 += wr2[y]     * hr[y];
                a1 += wr2[y + 1] * hr[y + 1];
                a2 += wr2[y + 2] * hr[y + 2];
                a3 += wr2[y + 3] * hr[y + 3];
            }
            for (; y < CUTN; ++y) a0 += wr2[y] * hr[y];
            const float v = (a0 + a1 + a2 + a3 + lin_b[512]) * fcg[512];
            const float m = 1.0f / (1.0f + __expf(-2.0f * v));
            float* row = t + ((size_t)b * FN + f) * TCP;
            row[512]        *= m;
            row[512 + CUTN] *= m;
        }
    }
}

// ---------------------------------------------------------------------------
// Prep: differenced transposed-conv weights.
// ---------------------------------------------------------------------------
__global__ __launch_bounds__(256) void k_wdiff(
    const float* __restrict__ wct, float* __restrict__ wd)
{
    const int i = blockIdx.x;    // 0..1025
    const int j = blockIdx.y;    // 0..3
    const int r = threadIdx.x;   // 0..255
    const int widx = (3 - j) * 256 + r;
    wd[((size_t)(j * TCN + i)) * 256 + r] =
        wct[((size_t)(i * 2)) * KW + widx] - wct[((size_t)(i * 2 + 1)) * KW + widx];
}

// ---------------------------------------------------------------------------
// Kernel 3: transposed conv as GEMV-per-(b,m) with differenced weights,
// fused softmax.
// ---------------------------------------------------------------------------
__global__ __launch_bounds__(256) void k_convt(
    const float* __restrict__ t, const float* __restrict__ wd,
    float* __restrict__ out)
{
    __shared__ __align__(16) float a[11 * TCN];
    __shared__ float red[1024];
    const int mt = blockIdx.x;   // 0..127
    const int b  = blockIdx.y;
    const int m0 = mt * 8;

    const float* tb = t + ((size_t)b * FN + m0 + 1) * TCP;
    for (int fr = 0; fr < 11; ++fr)
        for (int i = threadIdx.x; i < TCN; i += 256)
            a[fr * TCN + i] = tb[(size_t)fr * TCP + i];
    __syncthreads();

    const int rg = threadIdx.x & 63;
    const int kg = threadIdx.x >> 6;

    float acc[4][8];
#pragma unroll
    for (int q = 0; q < 4; ++q)
#pragma unroll
        for (int mm = 0; mm < 8; ++mm) acc[q][mm] = 0.0f;

    const float4* wp = (const float4*)wd + (size_t)(kg * TCN) * 64 + rg;
    const float*  ar = a + kg * TCN;

    for (int i = 0; i < TCN; ++i) {
        const float4 wv = wp[(size_t)i * 64];
#pragma unroll
        for (int mm = 0; mm < 8; ++mm) {
            const float av = ar[mm * TCN + i];
            acc[0][mm] += wv.x * av;
            acc[1][mm] += wv.y * av;
            acc[2][mm] += wv.z * av;
            acc[3][mm] += wv.w * av;
        }
    }

    float* ob = out + (size_t)b * 2 * TIME_N;
#pragma unroll 1
    for (int mm = 0; mm < 8; ++mm) {
        __syncthreads();
        red[kg * 256 + rg * 4 + 0] = acc[0][mm];
        red[kg * 256 + rg * 4 + 1] = acc[1][mm];
        red[kg * 256 + rg * 4 + 2] = acc[2][mm];
        red[kg * 256 + rg * 4 + 3] = acc[3][mm];
        __syncthreads();
        const float d = red[threadIdx.x] + red[256 + threadIdx.x] +
                        red[512 + threadIdx.x] + red[768 + threadIdx.x];
        const float p0 = 1.0f / (1.0f + __expf(-d));
        const int tau = (m0 + mm) * 256 + threadIdx.x;
        ob[tau]          = p0;
        ob[TIME_N + tau] = 1.0f - p0;
    }
}

extern "C" void kernel_launch(void* const* d_in, const int* in_sizes, int n_in,
                              void* d_out, int out_size, void* d_ws, size_t ws_size,
                              hipStream_t stream)
{
    const float* x    = (const float*)d_in[0];
    const float* c1w  = (const float*)d_in[1];
    const float* ing  = (const float*)d_in[2];
    const float* cb1w = (const float*)d_in[3];
    const float* cb1b = (const float*)d_in[4];
    const float* cb2w = (const float*)d_in[5];
    const float* cb2b = (const float*)d_in[6];
    const float* linw = (const float*)d_in[7];
    const float* linb = (const float*)d_in[8];
    const float* fcg  = (const float*)d_in[9];
    const float* ctw  = (const float*)d_in[10];
    float* out = (float*)d_out;

    float* t  = (float*)d_ws;                          // 32*1029*1028 f32
    float* wd = t + (size_t)BATCH * FN * TCP;          // 4104*256 f32
    unsigned short* xb  = (unsigned short*)(wd + (size_t)4 * TCN * 256); // 32*XLEN bf16
    unsigned short* wbf = xb + (size_t)BATCH * XLEN;   // 1152*1024 bf16

    hipLaunchKernelGGL(k_xpad, dim3(XLEN / 256, BATCH), dim3(256), 0, stream, x, xb);
    hipLaunchKernelGGL(k_wbf, dim3(CPAD), dim3(256), 0, stream, c1w, wbf);
    hipLaunchKernelGGL(k_wdiff, dim3(TCN, 4), dim3(256), 0, stream, ctw, wd);
    hipLaunchKernelGGL(k_conv1m, dim3(9, 9, BATCH), dim3(256), 0, stream,
                       xb, wbf, ing, t);
    hipLaunchKernelGGL(k_mask, dim3(129, BATCH), dim3(256), 0, stream,
                       t, cb1w, cb1b, cb2w, cb2b, linw, linb, fcg);
    hipLaunchKernelGGL(k_convt, dim3(128, BATCH), dim3(256), 0, stream,
                       t, wd, out);
}

// Round 3
// 647.588 us; speedup vs baseline: 11.7688x; 6.1714x over previous
//
#include <hip/hip_runtime.h>
#include <cstddef>
#include <cstdint>

#define TIME_N 262144
#define BATCH  32
#define KW     1024
#define ST     256
#define CUTN   513
#define TCN    1026
#define TCP    1028   // padded row stride for t (f32)
#define FN     1029   // frames
#define FPAD   1152
#define CPAD   1152
#define XLEN   (FPAD * ST + KW)   // 295936 bf16 per batch row

// mask GEMM dims
#define MROWS  (BATCH * FN)   // 32928
#define MP     33024          // 258*128
#define KPH    544            // 513 -> 17*32
#define NPH    640            // 513 -> 5*128
// convT GEMM dims
#define TBP    1032           // flat bf16 t row stride (16B-aligned)
#define FLATB  (FN * TBP)     // per-batch flat size
#define KPC    4128           // 4*1032, 129*32
#define NMASK  256

typedef __bf16 bf16x8 __attribute__((ext_vector_type(8)));
typedef float floatx4 __attribute__((ext_vector_type(4)));

__device__ __forceinline__ unsigned short f2bf(float f) {
    union { float f; unsigned u; } v; v.f = f;
    unsigned r = (v.u + 0x7fffu + ((v.u >> 16) & 1u)) >> 16;
    return (unsigned short)r;
}

__device__ __forceinline__ void load_lds16(const void* g, void* l) {
    __builtin_amdgcn_global_load_lds(
        (const __attribute__((address_space(1))) void*)g,
        (__attribute__((address_space(3))) void*)l, 16, 0, 0);
}

// ---------------------------------------------------------------------------
// Prep A: zero-padded bf16 copy of x.
// ---------------------------------------------------------------------------
__global__ __launch_bounds__(256) void k_xpad(
    const float* __restrict__ x, unsigned short* __restrict__ xb)
{
    const int p = blockIdx.x * 256 + threadIdx.x;
    const int b = blockIdx.y;
    const int g = p - KW;
    float v = (g >= 0 && g < TIME_N) ? x[(size_t)b * TIME_N + g] : 0.0f;
    xb[(size_t)b * XLEN + p] = f2bf(v);
}

// ---------------------------------------------------------------------------
// Prep B: bf16 conv1 weights padded to [1152][1024].
// ---------------------------------------------------------------------------
__global__ __launch_bounds__(256) void k_wbf(
    const float* __restrict__ w, unsigned short* __restrict__ wb)
{
    const int c = blockIdx.x;
    for (int k = threadIdx.x; k < KW; k += 256) {
        float v = (c < TCN) ? w[(size_t)c * KW + k] : 0.0f;
        wb[(size_t)c * KW + k] = f2bf(v);
    }
}

// ---------------------------------------------------------------------------
// Kernel 1 (MFMA): conv1 as bf16 GEMM, tanh(gamma*.) fused epilogue.
// ---------------------------------------------------------------------------
__global__ __launch_bounds__(256) void k_conv1m(
    const unsigned short* __restrict__ xb, const unsigned short* __restrict__ wb,
    const float* __restrict__ gamma, float* __restrict__ t)
{
    __shared__ __align__(16) unsigned short As[128 * 32];
    __shared__ __align__(16) unsigned short Bs[128 * 32];

    const int fb = blockIdx.x, cb = blockIdx.y, b = blockIdx.z;
    const int f0 = fb * 128, c0 = cb * 128;
    const int tid = threadIdx.x;

    const int s0 = tid, s1 = tid + 256;
    const int ar0 = s0 >> 2, aq0 = s0 & 3;
    const int ar1 = s1 >> 2, aq1 = s1 & 3;
    const unsigned short* xrow = xb + (size_t)b * XLEN;
    const unsigned short* ga0 = xrow + (size_t)(f0 + ar0) * ST + aq0 * 8;
    const unsigned short* ga1 = xrow + (size_t)(f0 + ar1) * ST + aq1 * 8;
    const unsigned short* gb0 = wb + (size_t)(c0 + ar0) * KW + aq0 * 8;
    const unsigned short* gb1 = wb + (size_t)(c0 + ar1) * KW + aq1 * 8;
    unsigned short* la0 = &As[s0 * 8];
    unsigned short* la1 = &As[s1 * 8];
    unsigned short* lb0 = &Bs[s0 * 8];
    unsigned short* lb1 = &Bs[s1 * 8];

    const int wave = tid >> 6, lane = tid & 63;
    const int lm = lane & 15, lq = lane >> 4;
    const int mw = (wave & 1) * 64, nw = (wave >> 1) * 64;
    const unsigned short* Ap = &As[(mw + lm) * 32 + lq * 8];
    const unsigned short* Bp = &Bs[(nw + lm) * 32 + lq * 8];

    floatx4 acc[4][4];
#pragma unroll
    for (int i = 0; i < 4; ++i)
#pragma unroll
        for (int j = 0; j < 4; ++j) acc[i][j] = (floatx4)0.0f;

    for (int ks = 0; ks < KW / 32; ++ks) {
        load_lds16(ga0, la0);
        load_lds16(ga1, la1);
        load_lds16(gb0, lb0);
        load_lds16(gb1, lb1);
        ga0 += 32; ga1 += 32; gb0 += 32; gb1 += 32;
        __syncthreads();

        bf16x8 afr[4], bfr[4];
#pragma unroll
        for (int mt = 0; mt < 4; ++mt) afr[mt] = *(const bf16x8*)(Ap + mt * 16 * 32);
#pragma unroll
        for (int nt = 0; nt < 4; ++nt) bfr[nt] = *(const bf16x8*)(Bp + nt * 16 * 32);
#pragma unroll
        for (int mt = 0; mt < 4; ++mt)
#pragma unroll
            for (int nt = 0; nt < 4; ++nt)
                acc[mt][nt] = __builtin_amdgcn_mfma_f32_16x16x32_bf16(
                    afr[mt], bfr[nt], acc[mt][nt], 0, 0, 0);
        __syncthreads();
    }

#pragma unroll
    for (int nt = 0; nt < 4; ++nt) {
        const int c = c0 + nw + nt * 16 + lm;
        if (c < TCN) {
            const float gv = gamma[c];
#pragma unroll
            for (int mt = 0; mt < 4; ++mt) {
#pragma unroll
                for (int r = 0; r < 4; ++r) {
                    const int f = f0 + mw + mt * 16 + lq * 4 + r;
                    if (f < FN) {
                        const float u = acc[mt][nt][r] * gv;
                        t[((size_t)b * FN + f) * TCP + c] =
                            2.0f / (1.0f + __expf(-2.0f * u)) - 1.0f;
                    }
                }
            }
        }
    }
}

// ---------------------------------------------------------------------------
// k_h: h[m][y] bf16, m = b*1029+f (row = t row m), padded [33024][544].
// ---------------------------------------------------------------------------
__global__ __launch_bounds__(256) void k_h(
    const float* __restrict__ t,
    const float* __restrict__ c1w, const float* __restrict__ c1b,
    const float* __restrict__ c2w, const float* __restrict__ c2b,
    unsigned short* __restrict__ h)
{
    const int m0 = blockIdx.x * 8;
    float w1[16], b1[8], w2[8];
#pragma unroll
    for (int o = 0; o < 8; ++o) {
        w1[2 * o]     = c1w[2 * o];
        w1[2 * o + 1] = c1w[2 * o + 1];
        b1[o] = c1b[o];
        w2[o] = c2w[o];
    }
    const float b2v = c2b[0];

    for (int idx = threadIdx.x; idx < 8 * KPH; idx += 256) {
        const int fl = idx / KPH;
        const int y  = idx - fl * KPH;
        const int m  = m0 + fl;
        float hv = 0.0f;
        if (m < MROWS && y < CUTN) {
            const float* row = t + (size_t)m * TCP;
            const float re = row[y];
            const float im = row[y + CUTN];
            float a2 = b2v;
#pragma unroll
            for (int o = 0; o < 8; ++o) {
                float a1 = fmaxf(re * w1[2 * o] + im * w1[2 * o + 1] + b1[o], 0.0f);
                a2 += a1 * w2[o];
            }
            hv = fmaxf(a2, 0.0f);
        }
        h[(size_t)m0 * KPH + idx] = f2bf(hv);
    }
}

// ---------------------------------------------------------------------------
// k_wlin: lin_w bf16 padded [640][544].
// ---------------------------------------------------------------------------
__global__ __launch_bounds__(256) void k_wlin(
    const float* __restrict__ lw, unsigned short* __restrict__ wlb)
{
    const int n = blockIdx.x;
    for (int k = threadIdx.x; k < KPH; k += 256) {
        float v = (n < CUTN && k < CUTN) ? lw[(size_t)n * CUTN + k] : 0.0f;
        wlb[(size_t)n * KPH + k] = f2bf(v);
    }
}

// ---------------------------------------------------------------------------
// k_maskm (MFMA): hh = H * Wlin^T; mask = sigmoid(2*(hh+b)*g); t *= mask.
// M=33024 (258 tiles), N=640 (5 tiles), K=544 (17 steps).
// ---------------------------------------------------------------------------
__global__ __launch_bounds__(256) void k_maskm(
    const unsigned short* __restrict__ h, const unsigned short* __restrict__ wlb,
    const float* __restrict__ linb, const float* __restrict__ fcg,
    float* __restrict__ t)
{
    __shared__ __align__(16) unsigned short As[128 * 32];
    __shared__ __align__(16) unsigned short Bs[128 * 32];

    const int m0 = blockIdx.x * 128, n0 = blockIdx.y * 128;
    const int tid = threadIdx.x;

    const int s0 = tid, s1 = tid + 256;
    const int ar0 = s0 >> 2, aq0 = s0 & 3;
    const int ar1 = s1 >> 2, aq1 = s1 & 3;
    const unsigned short* ga0 = h + (size_t)(m0 + ar0) * KPH + aq0 * 8;
    const unsigned short* ga1 = h + (size_t)(m0 + ar1) * KPH + aq1 * 8;
    const unsigned short* gb0 = wlb + (size_t)(n0 + ar0) * KPH + aq0 * 8;
    const unsigned short* gb1 = wlb + (size_t)(n0 + ar1) * KPH + aq1 * 8;
    unsigned short* la0 = &As[s0 * 8];
    unsigned short* la1 = &As[s1 * 8];
    unsigned short* lb0 = &Bs[s0 * 8];
    unsigned short* lb1 = &Bs[s1 * 8];

    const int wave = tid >> 6, lane = tid & 63;
    const int lm = lane & 15, lq = lane >> 4;
    const int mw = (wave & 1) * 64, nw = (wave >> 1) * 64;
    const unsigned short* Ap = &As[(mw + lm) * 32 + lq * 8];
    const unsigned short* Bp = &Bs[(nw + lm) * 32 + lq * 8];

    floatx4 acc[4][4];
#pragma unroll
    for (int i = 0; i < 4; ++i)
#pragma unroll
        for (int j = 0; j < 4; ++j) acc[i][j] = (floatx4)0.0f;

    for (int ks = 0; ks < KPH / 32; ++ks) {
        load_lds16(ga0, la0);
        load_lds16(ga1, la1);
        load_lds16(gb0, lb0);
        load_lds16(gb1, lb1);
        ga0 += 32; ga1 += 32; gb0 += 32; gb1 += 32;
        __syncthreads();

        bf16x8 afr[4], bfr[4];
#pragma unroll
        for (int mt = 0; mt < 4; ++mt) afr[mt] = *(const bf16x8*)(Ap + mt * 16 * 32);
#pragma unroll
        for (int nt = 0; nt < 4; ++nt) bfr[nt] = *(const bf16x8*)(Bp + nt * 16 * 32);
#pragma unroll
        for (int mt = 0; mt < 4; ++mt)
#pragma unroll
            for (int nt = 0; nt < 4; ++nt)
                acc[mt][nt] = __builtin_amdgcn_mfma_f32_16x16x32_bf16(
                    afr[mt], bfr[nt], acc[mt][nt], 0, 0, 0);
        __syncthreads();
    }

#pragma unroll
    for (int nt = 0; nt < 4; ++nt) {
        const int n = n0 + nw + nt * 16 + lm;
        if (n < CUTN) {
            const float lb = linb[n];
            const float gv = fcg[n];
#pragma unroll
            for (int mt = 0; mt < 4; ++mt) {
#pragma unroll
                for (int r = 0; r < 4; ++r) {
                    const int m = m0 + mw + mt * 16 + lq * 4 + r;
                    if (m < MROWS) {
                        const float v = (acc[mt][nt][r] + lb) * gv;
                        const float msk = 1.0f / (1.0f + __expf(-2.0f * v));
                        float* row = t + (size_t)m * TCP;
                        row[n]        *= msk;
                        row[n + CUTN] *= msk;
                    }
                }
            }
        }
    }
}

// ---------------------------------------------------------------------------
// k_tbf: masked t -> flat bf16 [b][f*1032 + i], 6 zero-pad tail per frame.
// ---------------------------------------------------------------------------
__global__ __launch_bounds__(256) void k_tbf(
    const float* __restrict__ t, unsigned short* __restrict__ tb2)
{
    const int f = blockIdx.x, b = blockIdx.y;
    const float* src = t + ((size_t)b * FN + f) * TCP;
    unsigned short* dst = tb2 + (size_t)b * FLATB + (size_t)f * TBP;
    for (int i = threadIdx.x; i < TBP; i += 256)
        dst[i] = (i < TCN) ? f2bf(src[i]) : (unsigned short)0;
}

// ---------------------------------------------------------------------------
// k_wdt: differenced transposed convT weights, bf16 [256][4128],
// k = j*1032 + i (i<1026 valid, else 0), value W[i,0,(3-j)*256+r]-W[i,1,...].
// ---------------------------------------------------------------------------
__global__ __launch_bounds__(256) void k_wdt(
    const float* __restrict__ wct, unsigned short* __restrict__ wdb)
{
    const int k = blockIdx.x;        // 0..4127
    const int r = threadIdx.x;       // 0..255
    const int j = k / TBP;
    const int i = k - j * TBP;
    float v = 0.0f;
    if (i < TCN) {
        const int widx = (3 - j) * 256 + r;
        v = wct[(size_t)(2 * i) * KW + widx] - wct[(size_t)(2 * i + 1) * KW + widx];
    }
    wdb[(size_t)r * KPC + k] = f2bf(v);
}

// ---------------------------------------------------------------------------
// k_convtm (MFMA): d[m_row][r] = A(tb2 windows) * Wd^T, softmax epilogue.
// M=32768 (256 tiles), N=256 (2 tiles), K=4128 (129 steps).
// ---------------------------------------------------------------------------
__global__ __launch_bounds__(256) void k_convtm(
    const unsigned short* __restrict__ tb2, const unsigned short* __restrict__ wdb,
    float* __restrict__ out)
{
    __shared__ __align__(16) unsigned short As[128 * 32];
    __shared__ __align__(16) unsigned short Bs[128 * 32];

    const int m0 = blockIdx.x * 128, n0 = blockIdx.y * 128;
    const int b   = m0 >> 10;
    const int ml0 = m0 & 1023;
    const int tid = threadIdx.x;

    const int s0 = tid, s1 = tid + 256;
    const int ar0 = s0 >> 2, aq0 = s0 & 3;
    const int ar1 = s1 >> 2, aq1 = s1 & 3;
    const unsigned short* tbb = tb2 + (size_t)b * FLATB;
    const unsigned short* ga0 = tbb + (size_t)(ml0 + ar0 + 1) * TBP + aq0 * 8;
    const unsigned short* ga1 = tbb + (size_t)(ml0 + ar1 + 1) * TBP + aq1 * 8;
    const unsigned short* gb0 = wdb + (size_t)(n0 + ar0) * KPC + aq0 * 8;
    const unsigned short* gb1 = wdb + (size_t)(n0 + ar1) * KPC + aq1 * 8;
    unsigned short* la0 = &As[s0 * 8];
    unsigned short* la1 = &As[s1 * 8];
    unsigned short* lb0 = &Bs[s0 * 8];
    unsigned short* lb1 = &Bs[s1 * 8];

    const int wave = tid >> 6, lane = tid & 63;
    const int lm = lane & 15, lq = lane >> 4;
    const int mw = (wave & 1) * 64, nw = (wave >> 1) * 64;
    const unsigned short* Ap = &As[(mw + lm) * 32 + lq * 8];
    const unsigned short* Bp = &Bs[(nw + lm) * 32 + lq * 8];

    floatx4 acc[4][4];
#pragma unroll
    for (int i = 0; i < 4; ++i)
#pragma unroll
        for (int j = 0; j < 4; ++j) acc[i][j] = (floatx4)0.0f;

    for (int ks = 0; ks < KPC / 32; ++ks) {
        load_lds16(ga0, la0);
        load_lds16(ga1, la1);
        load_lds16(gb0, lb0);
        load_lds16(gb1, lb1);
        ga0 += 32; ga1 += 32; gb0 += 32; gb1 += 32;
        __syncthreads();

        bf16x8 afr[4], bfr[4];
#pragma unroll
        for (int mt = 0; mt < 4; ++mt) afr[mt] = *(const bf16x8*)(Ap + mt * 16 * 32);
#pragma unroll
        for (int nt = 0; nt < 4; ++nt) bfr[nt] = *(const bf16x8*)(Bp + nt * 16 * 32);
#pragma unroll
        for (int mt = 0; mt < 4; ++mt)
#pragma unroll
            for (int nt = 0; nt < 4; ++nt)
                acc[mt][nt] = __builtin_amdgcn_mfma_f32_16x16x32_bf16(
                    afr[mt], bfr[nt], acc[mt][nt], 0, 0, 0);
        __syncthreads();
    }

    float* ob = out + (size_t)b * 2 * TIME_N;
#pragma unroll
    for (int nt = 0; nt < 4; ++nt) {
        const int n = n0 + nw + nt * 16 + lm;   // r in 0..255
#pragma unroll
        for (int mt = 0; mt < 4; ++mt) {
#pragma unroll
            for (int r = 0; r < 4; ++r) {
                const int m = ml0 + mw + mt * 16 + lq * 4 + r;   // 0..1023
                const float d = acc[mt][nt][r];
                const float p0 = 1.0f / (1.0f + __expf(-d));
                const int tau = m * 256 + n;
                ob[tau]          = p0;
                ob[TIME_N + tau] = 1.0f - p0;
            }
        }
    }
}

extern "C" void kernel_launch(void* const* d_in, const int* in_sizes, int n_in,
                              void* d_out, int out_size, void* d_ws, size_t ws_size,
                              hipStream_t stream)
{
    const float* x    = (const float*)d_in[0];
    const float* c1w  = (const float*)d_in[1];
    const float* ing  = (const float*)d_in[2];
    const float* cb1w = (const float*)d_in[3];
    const float* cb1b = (const float*)d_in[4];
    const float* cb2w = (const float*)d_in[5];
    const float* cb2b = (const float*)d_in[6];
    const float* linw = (const float*)d_in[7];
    const float* linb = (const float*)d_in[8];
    const float* fcg  = (const float*)d_in[9];
    const float* ctw  = (const float*)d_in[10];
    float* out = (float*)d_out;

    // ---- workspace layout (phase-aliased) ----
    float* t = (float*)d_ws;                               // 32*1029*1028 f32
    unsigned short* region = (unsigned short*)(t + (size_t)BATCH * FN * TCP);
    // phase 1: h | wlb | xb | wbf
    unsigned short* h   = region;                          // 33024*544
    unsigned short* wlb = h + (size_t)MP * KPH;            // 640*544
    unsigned short* xb  = wlb + (size_t)NPH * KPH;         // 32*XLEN
    unsigned short* wbf = xb + (size_t)BATCH * XLEN;       // 1152*1024
    // phase 2 (after k_maskm): tb2 | wdb  (aliases phase 1)
    unsigned short* tb2 = region;                          // 32*1029*1032
    unsigned short* wdb = tb2 + (size_t)BATCH * FLATB;     // 256*4128

    hipLaunchKernelGGL(k_xpad, dim3(XLEN / 256, BATCH), dim3(256), 0, stream, x, xb);
    hipLaunchKernelGGL(k_wbf, dim3(CPAD), dim3(256), 0, stream, c1w, wbf);
    hipLaunchKernelGGL(k_conv1m, dim3(9, 9, BATCH), dim3(256), 0, stream,
                       xb, wbf, ing, t);
    hipLaunchKernelGGL(k_h, dim3(MP / 8), dim3(256), 0, stream,
                       t, cb1w, cb1b, cb2w, cb2b, h);
    hipLaunchKernelGGL(k_wlin, dim3(NPH), dim3(256), 0, stream, linw, wlb);
    hipLaunchKernelGGL(k_maskm, dim3(MP / 128, NPH / 128), dim3(256), 0, stream,
                       h, wlb, linb, fcg, t);
    hipLaunchKernelGGL(k_tbf, dim3(FN, BATCH), dim3(256), 0, stream, t, tb2);
    hipLaunchKernelGGL(k_wdt, dim3(KPC), dim3(256), 0, stream, ctw, wdb);
    hipLaunchKernelGGL(k_convtm, dim3(256, 2), dim3(256), 0, stream,
                       tb2, wdb, out);
}

// Round 4
// 558.481 us; speedup vs baseline: 13.6465x; 1.1596x over previous
//
#include <hip/hip_runtime.h>
#include <cstddef>
#include <cstdint>

#define TIME_N 262144
#define BATCH  32
#define KW     1024
#define ST     256
#define CUTN   513
#define TCN    1026
#define FN     1029   // frames
#define FPAD   1152
#define CPAD   1152
#define XLEN   (FPAD * ST + KW)   // 295936 bf16 per batch row

// mask GEMM dims
#define MROWS  (BATCH * FN)   // 32928
#define MP     33024          // 258*128
#define KPH    544            // 513 -> 17*32
#define NPH    640            // 513 -> 5*128
// convT GEMM dims / flat bf16 t layout
#define TBP    1032           // flat bf16 t row stride (16B-aligned)
#define FLATB  (FN * TBP)     // per-batch flat size
#define KPC    4128           // 4*1032, 129*32

typedef __bf16 bf16x8 __attribute__((ext_vector_type(8)));
typedef float floatx4 __attribute__((ext_vector_type(4)));

__device__ __forceinline__ unsigned short f2bf(float f) {
    union { float f; unsigned u; } v; v.f = f;
    unsigned r = (v.u + 0x7fffu + ((v.u >> 16) & 1u)) >> 16;
    return (unsigned short)r;
}
__device__ __forceinline__ float bf2f(unsigned short s) {
    union { unsigned u; float f; } v; v.u = ((unsigned)s) << 16;
    return v.f;
}

__device__ __forceinline__ void load_lds16(const void* g, void* l) {
    __builtin_amdgcn_global_load_lds(
        (const __attribute__((address_space(1))) void*)g,
        (__attribute__((address_space(3))) void*)l, 16, 0, 0);
}

// ---------------------------------------------------------------------------
// Prep A: zero-padded bf16 copy of x.
// ---------------------------------------------------------------------------
__global__ __launch_bounds__(256) void k_xpad(
    const float* __restrict__ x, unsigned short* __restrict__ xb)
{
    const int p = blockIdx.x * 256 + threadIdx.x;
    const int b = blockIdx.y;
    const int g = p - KW;
    float v = (g >= 0 && g < TIME_N) ? x[(size_t)b * TIME_N + g] : 0.0f;
    xb[(size_t)b * XLEN + p] = f2bf(v);
}

// ---------------------------------------------------------------------------
// Prep B: bf16 conv1 weights padded to [1152][1024].
// ---------------------------------------------------------------------------
__global__ __launch_bounds__(256) void k_wbf(
    const float* __restrict__ w, unsigned short* __restrict__ wb)
{
    const int c = blockIdx.x;
    for (int k = threadIdx.x; k < KW; k += 256) {
        float v = (c < TCN) ? w[(size_t)c * KW + k] : 0.0f;
        wb[(size_t)c * KW + k] = f2bf(v);
    }
}

// ---------------------------------------------------------------------------
// Kernel 1 (MFMA): conv1 as bf16 GEMM, tanh(gamma*.) fused epilogue,
// writes bf16 directly into flat tb2 layout (stride 1032, zero tail).
// Grid: (b, fb, cb) so 32 consecutive blocks share one weight tile (L2).
// ---------------------------------------------------------------------------
__global__ __launch_bounds__(256) void k_conv1m(
    const unsigned short* __restrict__ xb, const unsigned short* __restrict__ wb,
    const float* __restrict__ gamma, unsigned short* __restrict__ tb2)
{
    __shared__ __align__(16) unsigned short As[128 * 32];
    __shared__ __align__(16) unsigned short Bs[128 * 32];

    const int b = blockIdx.x, fb = blockIdx.y, cb = blockIdx.z;
    const int f0 = fb * 128, c0 = cb * 128;
    const int tid = threadIdx.x;

    const int s0 = tid, s1 = tid + 256;
    const int ar0 = s0 >> 2, aq0 = s0 & 3;
    const int ar1 = s1 >> 2, aq1 = s1 & 3;
    const unsigned short* xrow = xb + (size_t)b * XLEN;
    const unsigned short* ga0 = xrow + (size_t)(f0 + ar0) * ST + aq0 * 8;
    const unsigned short* ga1 = xrow + (size_t)(f0 + ar1) * ST + aq1 * 8;
    const unsigned short* gb0 = wb + (size_t)(c0 + ar0) * KW + aq0 * 8;
    const unsigned short* gb1 = wb + (size_t)(c0 + ar1) * KW + aq1 * 8;
    unsigned short* la0 = &As[s0 * 8];
    unsigned short* la1 = &As[s1 * 8];
    unsigned short* lb0 = &Bs[s0 * 8];
    unsigned short* lb1 = &Bs[s1 * 8];

    const int wave = tid >> 6, lane = tid & 63;
    const int lm = lane & 15, lq = lane >> 4;
    const int mw = (wave & 1) * 64, nw = (wave >> 1) * 64;
    const unsigned short* Ap = &As[(mw + lm) * 32 + lq * 8];
    const unsigned short* Bp = &Bs[(nw + lm) * 32 + lq * 8];

    floatx4 acc[4][4];
#pragma unroll
    for (int i = 0; i < 4; ++i)
#pragma unroll
        for (int j = 0; j < 4; ++j) acc[i][j] = (floatx4)0.0f;

    for (int ks = 0; ks < KW / 32; ++ks) {
        load_lds16(ga0, la0);
        load_lds16(ga1, la1);
        load_lds16(gb0, lb0);
        load_lds16(gb1, lb1);
        ga0 += 32; ga1 += 32; gb0 += 32; gb1 += 32;
        __syncthreads();

        bf16x8 afr[4], bfr[4];
#pragma unroll
        for (int mt = 0; mt < 4; ++mt) afr[mt] = *(const bf16x8*)(Ap + mt * 16 * 32);
#pragma unroll
        for (int nt = 0; nt < 4; ++nt) bfr[nt] = *(const bf16x8*)(Bp + nt * 16 * 32);
#pragma unroll
        for (int mt = 0; mt < 4; ++mt)
#pragma unroll
            for (int nt = 0; nt < 4; ++nt)
                acc[mt][nt] = __builtin_amdgcn_mfma_f32_16x16x32_bf16(
                    afr[mt], bfr[nt], acc[mt][nt], 0, 0, 0);
        __syncthreads();
    }

    unsigned short* tbb = tb2 + (size_t)b * FLATB;
#pragma unroll
    for (int nt = 0; nt < 4; ++nt) {
        const int c = c0 + nw + nt * 16 + lm;
        if (c < TBP) {
            const float gv = (c < TCN) ? gamma[c] : 0.0f;
#pragma unroll
            for (int mt = 0; mt < 4; ++mt) {
#pragma unroll
                for (int r = 0; r < 4; ++r) {
                    const int f = f0 + mw + mt * 16 + lq * 4 + r;
                    if (f < FN) {
                        unsigned short o = 0;
                        if (c < TCN) {
                            const float u = acc[mt][nt][r] * gv;
                            o = f2bf(2.0f / (1.0f + __expf(-2.0f * u)) - 1.0f);
                        }
                        tbb[(size_t)f * TBP + c] = o;
                    }
                }
            }
        }
    }
}

// ---------------------------------------------------------------------------
// k_h: h[m][y] bf16 from bf16 tb2, m = b*1029+f, padded [33024][544].
// ---------------------------------------------------------------------------
__global__ __launch_bounds__(256) void k_h(
    const unsigned short* __restrict__ tb2,
    const float* __restrict__ c1w, const float* __restrict__ c1b,
    const float* __restrict__ c2w, const float* __restrict__ c2b,
    unsigned short* __restrict__ h)
{
    const int m0 = blockIdx.x * 8;
    float w1[16], b1[8], w2[8];
#pragma unroll
    for (int o = 0; o < 8; ++o) {
        w1[2 * o]     = c1w[2 * o];
        w1[2 * o + 1] = c1w[2 * o + 1];
        b1[o] = c1b[o];
        w2[o] = c2w[o];
    }
    const float b2v = c2b[0];

    for (int idx = threadIdx.x; idx < 8 * KPH; idx += 256) {
        const int fl = idx / KPH;
        const int y  = idx - fl * KPH;
        const int m  = m0 + fl;
        float hv = 0.0f;
        if (m < MROWS && y < CUTN) {
            const unsigned short* row = tb2 + (size_t)m * TBP;
            const float re = bf2f(row[y]);
            const float im = bf2f(row[y + CUTN]);
            float a2 = b2v;
#pragma unroll
            for (int o = 0; o < 8; ++o) {
                float a1 = fmaxf(re * w1[2 * o] + im * w1[2 * o + 1] + b1[o], 0.0f);
                a2 += a1 * w2[o];
            }
            hv = fmaxf(a2, 0.0f);
        }
        h[(size_t)m0 * KPH + idx] = f2bf(hv);
    }
}

// ---------------------------------------------------------------------------
// k_wlin: lin_w bf16 padded [640][544].
// ---------------------------------------------------------------------------
__global__ __launch_bounds__(256) void k_wlin(
    const float* __restrict__ lw, unsigned short* __restrict__ wlb)
{
    const int n = blockIdx.x;
    for (int k = threadIdx.x; k < KPH; k += 256) {
        float v = (n < CUTN && k < CUTN) ? lw[(size_t)n * CUTN + k] : 0.0f;
        wlb[(size_t)n * KPH + k] = f2bf(v);
    }
}

// ---------------------------------------------------------------------------
// k_maskm (MFMA): hh = H * Wlin^T; mask = sigmoid(2*(hh+b)*g);
// bf16 RMW: tb2 *= mask on both halves.
// ---------------------------------------------------------------------------
__global__ __launch_bounds__(256) void k_maskm(
    const unsigned short* __restrict__ h, const unsigned short* __restrict__ wlb,
    const float* __restrict__ linb, const float* __restrict__ fcg,
    unsigned short* __restrict__ tb2)
{
    __shared__ __align__(16) unsigned short As[128 * 32];
    __shared__ __align__(16) unsigned short Bs[128 * 32];

    const int m0 = blockIdx.x * 128, n0 = blockIdx.y * 128;
    const int tid = threadIdx.x;

    const int s0 = tid, s1 = tid + 256;
    const int ar0 = s0 >> 2, aq0 = s0 & 3;
    const int ar1 = s1 >> 2, aq1 = s1 & 3;
    const unsigned short* ga0 = h + (size_t)(m0 + ar0) * KPH + aq0 * 8;
    const unsigned short* ga1 = h + (size_t)(m0 + ar1) * KPH + aq1 * 8;
    const unsigned short* gb0 = wlb + (size_t)(n0 + ar0) * KPH + aq0 * 8;
    const unsigned short* gb1 = wlb + (size_t)(n0 + ar1) * KPH + aq1 * 8;
    unsigned short* la0 = &As[s0 * 8];
    unsigned short* la1 = &As[s1 * 8];
    unsigned short* lb0 = &Bs[s0 * 8];
    unsigned short* lb1 = &Bs[s1 * 8];

    const int wave = tid >> 6, lane = tid & 63;
    const int lm = lane & 15, lq = lane >> 4;
    const int mw = (wave & 1) * 64, nw = (wave >> 1) * 64;
    const unsigned short* Ap = &As[(mw + lm) * 32 + lq * 8];
    const unsigned short* Bp = &Bs[(nw + lm) * 32 + lq * 8];

    floatx4 acc[4][4];
#pragma unroll
    for (int i = 0; i < 4; ++i)
#pragma unroll
        for (int j = 0; j < 4; ++j) acc[i][j] = (floatx4)0.0f;

    for (int ks = 0; ks < KPH / 32; ++ks) {
        load_lds16(ga0, la0);
        load_lds16(ga1, la1);
        load_lds16(gb0, lb0);
        load_lds16(gb1, lb1);
        ga0 += 32; ga1 += 32; gb0 += 32; gb1 += 32;
        __syncthreads();

        bf16x8 afr[4], bfr[4];
#pragma unroll
        for (int mt = 0; mt < 4; ++mt) afr[mt] = *(const bf16x8*)(Ap + mt * 16 * 32);
#pragma unroll
        for (int nt = 0; nt < 4; ++nt) bfr[nt] = *(const bf16x8*)(Bp + nt * 16 * 32);
#pragma unroll
        for (int mt = 0; mt < 4; ++mt)
#pragma unroll
            for (int nt = 0; nt < 4; ++nt)
                acc[mt][nt] = __builtin_amdgcn_mfma_f32_16x16x32_bf16(
                    afr[mt], bfr[nt], acc[mt][nt], 0, 0, 0);
        __syncthreads();
    }

#pragma unroll
    for (int nt = 0; nt < 4; ++nt) {
        const int n = n0 + nw + nt * 16 + lm;
        if (n < CUTN) {
            const float lb = linb[n];
            const float gv = fcg[n];
#pragma unroll
            for (int mt = 0; mt < 4; ++mt) {
#pragma unroll
                for (int r = 0; r < 4; ++r) {
                    const int m = m0 + mw + mt * 16 + lq * 4 + r;
                    if (m < MROWS) {
                        const float v = (acc[mt][nt][r] + lb) * gv;
                        const float msk = 1.0f / (1.0f + __expf(-2.0f * v));
                        unsigned short* row = tb2 + (size_t)m * TBP;
                        row[n]        = f2bf(bf2f(row[n]) * msk);
                        row[n + CUTN] = f2bf(bf2f(row[n + CUTN]) * msk);
                    }
                }
            }
        }
    }
}

// ---------------------------------------------------------------------------
// k_wdt: differenced transposed convT weights, bf16 [256][4128].
// ---------------------------------------------------------------------------
__global__ __launch_bounds__(256) void k_wdt(
    const float* __restrict__ wct, unsigned short* __restrict__ wdb)
{
    const int k = blockIdx.x;        // 0..4127
    const int r = threadIdx.x;       // 0..255
    const int j = k / TBP;
    const int i = k - j * TBP;
    float v = 0.0f;
    if (i < TCN) {
        const int widx = (3 - j) * 256 + r;
        v = wct[(size_t)(2 * i) * KW + widx] - wct[(size_t)(2 * i + 1) * KW + widx];
    }
    wdb[(size_t)r * KPC + k] = f2bf(v);
}

// ---------------------------------------------------------------------------
// k_convtm (MFMA): d[m][r] = A(tb2 windows) * Wd^T, fused sigmoid softmax.
// M=32768 (256 tiles), N=256 (2 tiles), K=4128 (129 steps).
// ---------------------------------------------------------------------------
__global__ __launch_bounds__(256) void k_convtm(
    const unsigned short* __restrict__ tb2, const unsigned short* __restrict__ wdb,
    float* __restrict__ out)
{
    __shared__ __align__(16) unsigned short As[128 * 32];
    __shared__ __align__(16) unsigned short Bs[128 * 32];

    const int m0 = blockIdx.x * 128, n0 = blockIdx.y * 128;
    const int b   = m0 >> 10;
    const int ml0 = m0 & 1023;
    const int tid = threadIdx.x;

    const int s0 = tid, s1 = tid + 256;
    const int ar0 = s0 >> 2, aq0 = s0 & 3;
    const int ar1 = s1 >> 2, aq1 = s1 & 3;
    const unsigned short* tbb = tb2 + (size_t)b * FLATB;
    const unsigned short* ga0 = tbb + (size_t)(ml0 + ar0 + 1) * TBP + aq0 * 8;
    const unsigned short* ga1 = tbb + (size_t)(ml0 + ar1 + 1) * TBP + aq1 * 8;
    const unsigned short* gb0 = wdb + (size_t)(n0 + ar0) * KPC + aq0 * 8;
    const unsigned short* gb1 = wdb + (size_t)(n0 + ar1) * KPC + aq1 * 8;
    unsigned short* la0 = &As[s0 * 8];
    unsigned short* la1 = &As[s1 * 8];
    unsigned short* lb0 = &Bs[s0 * 8];
    unsigned short* lb1 = &Bs[s1 * 8];

    const int wave = tid >> 6, lane = tid & 63;
    const int lm = lane & 15, lq = lane >> 4;
    const int mw = (wave & 1) * 64, nw = (wave >> 1) * 64;
    const unsigned short* Ap = &As[(mw + lm) * 32 + lq * 8];
    const unsigned short* Bp = &Bs[(nw + lm) * 32 + lq * 8];

    floatx4 acc[4][4];
#pragma unroll
    for (int i = 0; i < 4; ++i)
#pragma unroll
        for (int j = 0; j < 4; ++j) acc[i][j] = (floatx4)0.0f;

    for (int ks = 0; ks < KPC / 32; ++ks) {
        load_lds16(ga0, la0);
        load_lds16(ga1, la1);
        load_lds16(gb0, lb0);
        load_lds16(gb1, lb1);
        ga0 += 32; ga1 += 32; gb0 += 32; gb1 += 32;
        __syncthreads();

        bf16x8 afr[4], bfr[4];
#pragma unroll
        for (int mt = 0; mt < 4; ++mt) afr[mt] = *(const bf16x8*)(Ap + mt * 16 * 32);
#pragma unroll
        for (int nt = 0; nt < 4; ++nt) bfr[nt] = *(const bf16x8*)(Bp + nt * 16 * 32);
#pragma unroll
        for (int mt = 0; mt < 4; ++mt)
#pragma unroll
            for (int nt = 0; nt < 4; ++nt)
                acc[mt][nt] = __builtin_amdgcn_mfma_f32_16x16x32_bf16(
                    afr[mt], bfr[nt], acc[mt][nt], 0, 0, 0);
        __syncthreads();
    }

    float* ob = out + (size_t)b * 2 * TIME_N;
#pragma unroll
    for (int nt = 0; nt < 4; ++nt) {
        const int n = n0 + nw + nt * 16 + lm;
#pragma unroll
        for (int mt = 0; mt < 4; ++mt) {
#pragma unroll
            for (int r = 0; r < 4; ++r) {
                const int m = ml0 + mw + mt * 16 + lq * 4 + r;
                const float d = acc[mt][nt][r];
                const float p0 = 1.0f / (1.0f + __expf(-d));
                const int tau = m * 256 + n;
                ob[tau]          = p0;
                ob[TIME_N + tau] = 1.0f - p0;
            }
        }
    }
}

extern "C" void kernel_launch(void* const* d_in, const int* in_sizes, int n_in,
                              void* d_out, int out_size, void* d_ws, size_t ws_size,
                              hipStream_t stream)
{
    const float* x    = (const float*)d_in[0];
    const float* c1w  = (const float*)d_in[1];
    const float* ing  = (const float*)d_in[2];
    const float* cb1w = (const float*)d_in[3];
    const float* cb1b = (const float*)d_in[4];
    const float* cb2w = (const float*)d_in[5];
    const float* cb2b = (const float*)d_in[6];
    const float* linw = (const float*)d_in[7];
    const float* linb = (const float*)d_in[8];
    const float* fcg  = (const float*)d_in[9];
    const float* ctw  = (const float*)d_in[10];
    float* out = (float*)d_out;

    // ---- workspace layout (no aliasing needed; all bf16) ----
    unsigned short* tb2 = (unsigned short*)d_ws;           // 32*1029*1032
    unsigned short* h   = tb2 + (size_t)BATCH * FLATB;     // 33024*544
    unsigned short* wlb = h + (size_t)MP * KPH;            // 640*544
    unsigned short* xb  = wlb + (size_t)NPH * KPH;         // 32*XLEN
    unsigned short* wbf = xb + (size_t)BATCH * XLEN;       // 1152*1024
    unsigned short* wdb = wbf + (size_t)CPAD * KW;         // 256*4128

    hipLaunchKernelGGL(k_xpad, dim3(XLEN / 256, BATCH), dim3(256), 0, stream, x, xb);
    hipLaunchKernelGGL(k_wbf, dim3(CPAD), dim3(256), 0, stream, c1w, wbf);
    hipLaunchKernelGGL(k_conv1m, dim3(BATCH, 9, 9), dim3(256), 0, stream,
                       xb, wbf, ing, tb2);
    hipLaunchKernelGGL(k_h, dim3(MP / 8), dim3(256), 0, stream,
                       tb2, cb1w, cb1b, cb2w, cb2b, h);
    hipLaunchKernelGGL(k_wlin, dim3(NPH), dim3(256), 0, stream, linw, wlb);
    hipLaunchKernelGGL(k_maskm, dim3(MP / 128, NPH / 128), dim3(256), 0, stream,
                       h, wlb, linb, fcg, tb2);
    hipLaunchKernelGGL(k_wdt, dim3(KPC), dim3(256), 0, stream, ctw, wdb);
    hipLaunchKernelGGL(k_convtm, dim3(256, 2), dim3(256), 0, stream,
                       tb2, wdb, out);
}

// Round 5
// 536.723 us; speedup vs baseline: 14.1997x; 1.0405x over previous
//
#include <hip/hip_runtime.h>
#include <cstddef>
#include <cstdint>

#define TIME_N 262144
#define BATCH  32
#define KW     1024
#define ST     256
#define CUTN   513
#define TCN    1026
#define FN     1029   // frames
#define FPAD   1152
#define CPAD   1152
#define XLEN   (FPAD * ST + KW)   // 295936 bf16 per batch row

// mask GEMM dims
#define MROWS  (BATCH * FN)   // 32928
#define MP     33024          // 258*128
#define KPH    544            // 513 -> 17*32
#define NPH    640            // 513 -> 5*128
// convT GEMM dims / flat bf16 t layout (re/im PAIR-INTERLEAVED: col 2y=re_y, 2y+1=im_y)
#define TBP    1032           // flat bf16 t row stride (16B-aligned)
#define FLATB  (FN * TBP)     // per-batch flat size
#define KPC    4128           // 4*1032, 129*32

typedef __bf16 bf16x8 __attribute__((ext_vector_type(8)));
typedef float floatx4 __attribute__((ext_vector_type(4)));

__device__ __forceinline__ unsigned short f2bf(float f) {
    union { float f; unsigned u; } v; v.f = f;
    unsigned r = (v.u + 0x7fffu + ((v.u >> 16) & 1u)) >> 16;
    return (unsigned short)r;
}
__device__ __forceinline__ float bf2f(unsigned short s) {
    union { unsigned u; float f; } v; v.u = ((unsigned)s) << 16;
    return v.f;
}
// interleaved column n -> original channel index
__device__ __forceinline__ int permch(int n) {
    return (n & 1) ? (CUTN + (n >> 1)) : (n >> 1);
}

__device__ __forceinline__ void load_lds16(const void* g, void* l) {
    __builtin_amdgcn_global_load_lds(
        (const __attribute__((address_space(1))) void*)g,
        (__attribute__((address_space(3))) void*)l, 16, 0, 0);
}

// ---------------------------------------------------------------------------
// Prep A: zero-padded bf16 copy of x.
// ---------------------------------------------------------------------------
__global__ __launch_bounds__(256) void k_xpad(
    const float* __restrict__ x, unsigned short* __restrict__ xb)
{
    const int p = blockIdx.x * 256 + threadIdx.x;
    const int b = blockIdx.y;
    const int g = p - KW;
    float v = (g >= 0 && g < TIME_N) ? x[(size_t)b * TIME_N + g] : 0.0f;
    xb[(size_t)b * XLEN + p] = f2bf(v);
}

// ---------------------------------------------------------------------------
// Prep B: bf16 conv1 weights, rows PERMUTED to pair-interleaved order,
// padded to [1152][1024].
// ---------------------------------------------------------------------------
__global__ __launch_bounds__(256) void k_wbf(
    const float* __restrict__ w, unsigned short* __restrict__ wb)
{
    const int n = blockIdx.x;                 // 0..1151 (interleaved index)
    const int ch = (n < TCN) ? permch(n) : 0;
    for (int k = threadIdx.x; k < KW; k += 256) {
        float v = (n < TCN) ? w[(size_t)ch * KW + k] : 0.0f;
        wb[(size_t)n * KW + k] = f2bf(v);
    }
}

// ---------------------------------------------------------------------------
// Kernel 1 (MFMA): conv1 as bf16 GEMM; epilogue does tanh(gamma*.),
// writes pair-interleaved bf16 tb2 AND computes h = MLP(re,im) via
// lane-pair shuffle (re/im are adjacent lanes). k_h eliminated.
// Grid (b, fb, cb) for L2 weight-tile sharing.
// ---------------------------------------------------------------------------
__global__ __launch_bounds__(256) void k_conv1m(
    const unsigned short* __restrict__ xb, const unsigned short* __restrict__ wb,
    const float* __restrict__ gamma,
    const float* __restrict__ c1w, const float* __restrict__ c1b,
    const float* __restrict__ c2w, const float* __restrict__ c2b,
    unsigned short* __restrict__ tb2, unsigned short* __restrict__ h)
{
    __shared__ __align__(16) unsigned short As[128 * 32];
    __shared__ __align__(16) unsigned short Bs[128 * 32];

    const int b = blockIdx.x, fb = blockIdx.y, cb = blockIdx.z;
    const int f0 = fb * 128, c0 = cb * 128;
    const int tid = threadIdx.x;

    const int s0 = tid, s1 = tid + 256;
    const int ar0 = s0 >> 2, aq0 = s0 & 3;
    const int ar1 = s1 >> 2, aq1 = s1 & 3;
    const unsigned short* xrow = xb + (size_t)b * XLEN;
    const unsigned short* ga0 = xrow + (size_t)(f0 + ar0) * ST + aq0 * 8;
    const unsigned short* ga1 = xrow + (size_t)(f0 + ar1) * ST + aq1 * 8;
    const unsigned short* gb0 = wb + (size_t)(c0 + ar0) * KW + aq0 * 8;
    const unsigned short* gb1 = wb + (size_t)(c0 + ar1) * KW + aq1 * 8;
    unsigned short* la0 = &As[s0 * 8];
    unsigned short* la1 = &As[s1 * 8];
    unsigned short* lb0 = &Bs[s0 * 8];
    unsigned short* lb1 = &Bs[s1 * 8];

    const int wave = tid >> 6, lane = tid & 63;
    const int lm = lane & 15, lq = lane >> 4;
    const int mw = (wave & 1) * 64, nw = (wave >> 1) * 64;
    const unsigned short* Ap = &As[(mw + lm) * 32 + lq * 8];
    const unsigned short* Bp = &Bs[(nw + lm) * 32 + lq * 8];

    floatx4 acc[4][4];
#pragma unroll
    for (int i = 0; i < 4; ++i)
#pragma unroll
        for (int j = 0; j < 4; ++j) acc[i][j] = (floatx4)0.0f;

    for (int ks = 0; ks < KW / 32; ++ks) {
        load_lds16(ga0, la0);
        load_lds16(ga1, la1);
        load_lds16(gb0, lb0);
        load_lds16(gb1, lb1);
        ga0 += 32; ga1 += 32; gb0 += 32; gb1 += 32;
        __syncthreads();

        bf16x8 afr[4], bfr[4];
#pragma unroll
        for (int mt = 0; mt < 4; ++mt) afr[mt] = *(const bf16x8*)(Ap + mt * 16 * 32);
#pragma unroll
        for (int nt = 0; nt < 4; ++nt) bfr[nt] = *(const bf16x8*)(Bp + nt * 16 * 32);
#pragma unroll
        for (int mt = 0; mt < 4; ++mt)
#pragma unroll
            for (int nt = 0; nt < 4; ++nt)
                acc[mt][nt] = __builtin_amdgcn_mfma_f32_16x16x32_bf16(
                    afr[mt], bfr[nt], acc[mt][nt], 0, 0, 0);
        __syncthreads();
    }

    // epilogue (uniform small params -> scalar regs)
    float w1[16], b1[8], w2[8];
#pragma unroll
    for (int o = 0; o < 8; ++o) {
        w1[2 * o]     = c1w[2 * o];
        w1[2 * o + 1] = c1w[2 * o + 1];
        b1[o] = c1b[o];
        w2[o] = c2w[o];
    }
    const float b2v = c2b[0];

    unsigned short* tbb = tb2 + (size_t)b * FLATB;
    const bool evenlane = ((lane & 1) == 0);
#pragma unroll
    for (int nt = 0; nt < 4; ++nt) {
        const int n = c0 + nw + nt * 16 + lm;
        const float gv = (n < TCN) ? gamma[permch(n)] : 0.0f;
#pragma unroll
        for (int mt = 0; mt < 4; ++mt) {
#pragma unroll
            for (int r = 0; r < 4; ++r) {
                const int f = f0 + mw + mt * 16 + lq * 4 + r;
                const float u = acc[mt][nt][r] * gv;
                const float tv = 2.0f / (1.0f + __expf(-2.0f * u)) - 1.0f;
                const float tim = __shfl_xor(tv, 1);   // all lanes execute
                if (f < FN && evenlane) {
                    if (n < TBP) {
                        const unsigned pr = (unsigned)f2bf(tv) |
                                            ((unsigned)f2bf(tim) << 16);
                        *(unsigned*)&tbb[(size_t)f * TBP + n] = pr;
                    }
                    if (n < TCN) {
                        float a2 = b2v;
#pragma unroll
                        for (int o = 0; o < 8; ++o) {
                            const float a1 = fmaxf(
                                tv * w1[2 * o] + tim * w1[2 * o + 1] + b1[o], 0.0f);
                            a2 += a1 * w2[o];
                        }
                        h[(size_t)((size_t)b * FN + f) * KPH + (n >> 1)] =
                            f2bf(fmaxf(a2, 0.0f));
                    }
                }
            }
        }
    }
}

// ---------------------------------------------------------------------------
// k_wlin: lin_w bf16 padded [640][544].
// ---------------------------------------------------------------------------
__global__ __launch_bounds__(256) void k_wlin(
    const float* __restrict__ lw, unsigned short* __restrict__ wlb)
{
    const int n = blockIdx.x;
    for (int k = threadIdx.x; k < KPH; k += 256) {
        float v = (n < CUTN && k < CUTN) ? lw[(size_t)n * CUTN + k] : 0.0f;
        wlb[(size_t)n * KPH + k] = f2bf(v);
    }
}

// ---------------------------------------------------------------------------
// k_maskm (MFMA): hh = H * Wlin^T; mask = sigmoid(2*(hh+b)*g);
// RMW: one aligned uint per (m,y) scales the (re,im) pair in tb2.
// ---------------------------------------------------------------------------
__global__ __launch_bounds__(256) void k_maskm(
    const unsigned short* __restrict__ h, const unsigned short* __restrict__ wlb,
    const float* __restrict__ linb, const float* __restrict__ fcg,
    unsigned* __restrict__ tbu)
{
    __shared__ __align__(16) unsigned short As[128 * 32];
    __shared__ __align__(16) unsigned short Bs[128 * 32];

    const int m0 = blockIdx.x * 128, n0 = blockIdx.y * 128;
    const int tid = threadIdx.x;

    const int s0 = tid, s1 = tid + 256;
    const int ar0 = s0 >> 2, aq0 = s0 & 3;
    const int ar1 = s1 >> 2, aq1 = s1 & 3;
    const unsigned short* ga0 = h + (size_t)(m0 + ar0) * KPH + aq0 * 8;
    const unsigned short* ga1 = h + (size_t)(m0 + ar1) * KPH + aq1 * 8;
    const unsigned short* gb0 = wlb + (size_t)(n0 + ar0) * KPH + aq0 * 8;
    const unsigned short* gb1 = wlb + (size_t)(n0 + ar1) * KPH + aq1 * 8;
    unsigned short* la0 = &As[s0 * 8];
    unsigned short* la1 = &As[s1 * 8];
    unsigned short* lb0 = &Bs[s0 * 8];
    unsigned short* lb1 = &Bs[s1 * 8];

    const int wave = tid >> 6, lane = tid & 63;
    const int lm = lane & 15, lq = lane >> 4;
    const int mw = (wave & 1) * 64, nw = (wave >> 1) * 64;
    const unsigned short* Ap = &As[(mw + lm) * 32 + lq * 8];
    const unsigned short* Bp = &Bs[(nw + lm) * 32 + lq * 8];

    floatx4 acc[4][4];
#pragma unroll
    for (int i = 0; i < 4; ++i)
#pragma unroll
        for (int j = 0; j < 4; ++j) acc[i][j] = (floatx4)0.0f;

    for (int ks = 0; ks < KPH / 32; ++ks) {
        load_lds16(ga0, la0);
        load_lds16(ga1, la1);
        load_lds16(gb0, lb0);
        load_lds16(gb1, lb1);
        ga0 += 32; ga1 += 32; gb0 += 32; gb1 += 32;
        __syncthreads();

        bf16x8 afr[4], bfr[4];
#pragma unroll
        for (int mt = 0; mt < 4; ++mt) afr[mt] = *(const bf16x8*)(Ap + mt * 16 * 32);
#pragma unroll
        for (int nt = 0; nt < 4; ++nt) bfr[nt] = *(const bf16x8*)(Bp + nt * 16 * 32);
#pragma unroll
        for (int mt = 0; mt < 4; ++mt)
#pragma unroll
            for (int nt = 0; nt < 4; ++nt)
                acc[mt][nt] = __builtin_amdgcn_mfma_f32_16x16x32_bf16(
                    afr[mt], bfr[nt], acc[mt][nt], 0, 0, 0);
        __syncthreads();
    }

#pragma unroll
    for (int nt = 0; nt < 4; ++nt) {
        const int y = n0 + nw + nt * 16 + lm;
        if (y < CUTN) {
            const float lb = linb[y];
            const float gv = fcg[y];
#pragma unroll
            for (int mt = 0; mt < 4; ++mt) {
#pragma unroll
                for (int r = 0; r < 4; ++r) {
                    const int m = m0 + mw + mt * 16 + lq * 4 + r;
                    if (m < MROWS) {
                        const float v = (acc[mt][nt][r] + lb) * gv;
                        const float msk = 1.0f / (1.0f + __expf(-2.0f * v));
                        unsigned* p = tbu + (size_t)m * (TBP / 2) + y;
                        const unsigned u = *p;
                        const float re = bf2f((unsigned short)(u & 0xffffu)) * msk;
                        const float im = bf2f((unsigned short)(u >> 16)) * msk;
                        *p = (unsigned)f2bf(re) | ((unsigned)f2bf(im) << 16);
                    }
                }
            }
        }
    }
}

// ---------------------------------------------------------------------------
// k_wdt: differenced transposed convT weights, bf16 [256][4128],
// column n uses the SAME pair-interleaved channel permutation as tb2.
// ---------------------------------------------------------------------------
__global__ __launch_bounds__(256) void k_wdt(
    const float* __restrict__ wct, unsigned short* __restrict__ wdb)
{
    const int k = blockIdx.x;        // 0..4127
    const int r = threadIdx.x;       // 0..255
    const int j = k / TBP;
    const int n = k - j * TBP;
    float v = 0.0f;
    if (n < TCN) {
        const int ch = permch(n);
        const int widx = (3 - j) * 256 + r;
        v = wct[(size_t)(2 * ch) * KW + widx] - wct[(size_t)(2 * ch + 1) * KW + widx];
    }
    wdb[(size_t)r * KPC + k] = f2bf(v);
}

// ---------------------------------------------------------------------------
// k_convtm (MFMA): d[m][r] = A(tb2 windows) * Wd^T, fused sigmoid softmax.
// ---------------------------------------------------------------------------
__global__ __launch_bounds__(256) void k_convtm(
    const unsigned short* __restrict__ tb2, const unsigned short* __restrict__ wdb,
    float* __restrict__ out)
{
    __shared__ __align__(16) unsigned short As[128 * 32];
    __shared__ __align__(16) unsigned short Bs[128 * 32];

    const int m0 = blockIdx.x * 128, n0 = blockIdx.y * 128;
    const int b   = m0 >> 10;
    const int ml0 = m0 & 1023;
    const int tid = threadIdx.x;

    const int s0 = tid, s1 = tid + 256;
    const int ar0 = s0 >> 2, aq0 = s0 & 3;
    const int ar1 = s1 >> 2, aq1 = s1 & 3;
    const unsigned short* tbb = tb2 + (size_t)b * FLATB;
    const unsigned short* ga0 = tbb + (size_t)(ml0 + ar0 + 1) * TBP + aq0 * 8;
    const unsigned short* ga1 = tbb + (size_t)(ml0 + ar1 + 1) * TBP + aq1 * 8;
    const unsigned short* gb0 = wdb + (size_t)(n0 + ar0) * KPC + aq0 * 8;
    const unsigned short* gb1 = wdb + (size_t)(n0 + ar1) * KPC + aq1 * 8;
    unsigned short* la0 = &As[s0 * 8];
    unsigned short* la1 = &As[s1 * 8];
    unsigned short* lb0 = &Bs[s0 * 8];
    unsigned short* lb1 = &Bs[s1 * 8];

    const int wave = tid >> 6, lane = tid & 63;
    const int lm = lane & 15, lq = lane >> 4;
    const int mw = (wave & 1) * 64, nw = (wave >> 1) * 64;
    const unsigned short* Ap = &As[(mw + lm) * 32 + lq * 8];
    const unsigned short* Bp = &Bs[(nw + lm) * 32 + lq * 8];

    floatx4 acc[4][4];
#pragma unroll
    for (int i = 0; i < 4; ++i)
#pragma unroll
        for (int j = 0; j < 4; ++j) acc[i][j] = (floatx4)0.0f;

    for (int ks = 0; ks < KPC / 32; ++ks) {
        load_lds16(ga0, la0);
        load_lds16(ga1, la1);
        load_lds16(gb0, lb0);
        load_lds16(gb1, lb1);
        ga0 += 32; ga1 += 32; gb0 += 32; gb1 += 32;
        __syncthreads();

        bf16x8 afr[4], bfr[4];
#pragma unroll
        for (int mt = 0; mt < 4; ++mt) afr[mt] = *(const bf16x8*)(Ap + mt * 16 * 32);
#pragma unroll
        for (int nt = 0; nt < 4; ++nt) bfr[nt] = *(const bf16x8*)(Bp + nt * 16 * 32);
#pragma unroll
        for (int mt = 0; mt < 4; ++mt)
#pragma unroll
            for (int nt = 0; nt < 4; ++nt)
                acc[mt][nt] = __builtin_amdgcn_mfma_f32_16x16x32_bf16(
                    afr[mt], bfr[nt], acc[mt][nt], 0, 0, 0);
        __syncthreads();
    }

    float* ob = out + (size_t)b * 2 * TIME_N;
#pragma unroll
    for (int nt = 0; nt < 4; ++nt) {
        const int n = n0 + nw + nt * 16 + lm;
#pragma unroll
        for (int mt = 0; mt < 4; ++mt) {
#pragma unroll
            for (int r = 0; r < 4; ++r) {
                const int m = ml0 + mw + mt * 16 + lq * 4 + r;
                const float d = acc[mt][nt][r];
                const float p0 = 1.0f / (1.0f + __expf(-d));
                const int tau = m * 256 + n;
                ob[tau]          = p0;
                ob[TIME_N + tau] = 1.0f - p0;
            }
        }
    }
}

extern "C" void kernel_launch(void* const* d_in, const int* in_sizes, int n_in,
                              void* d_out, int out_size, void* d_ws, size_t ws_size,
                              hipStream_t stream)
{
    const float* x    = (const float*)d_in[0];
    const float* c1w  = (const float*)d_in[1];
    const float* ing  = (const float*)d_in[2];
    const float* cb1w = (const float*)d_in[3];
    const float* cb1b = (const float*)d_in[4];
    const float* cb2w = (const float*)d_in[5];
    const float* cb2b = (const float*)d_in[6];
    const float* linw = (const float*)d_in[7];
    const float* linb = (const float*)d_in[8];
    const float* fcg  = (const float*)d_in[9];
    const float* ctw  = (const float*)d_in[10];
    float* out = (float*)d_out;

    // ---- workspace layout (all bf16) ----
    unsigned short* tb2 = (unsigned short*)d_ws;           // 32*1029*1032
    unsigned short* h   = tb2 + (size_t)BATCH * FLATB;     // 33024*544
    unsigned short* wlb = h + (size_t)MP * KPH;            // 640*544
    unsigned short* xb  = wlb + (size_t)NPH * KPH;         // 32*XLEN
    unsigned short* wbf = xb + (size_t)BATCH * XLEN;       // 1152*1024
    unsigned short* wdb = wbf + (size_t)CPAD * KW;         // 256*4128

    hipLaunchKernelGGL(k_xpad, dim3(XLEN / 256, BATCH), dim3(256), 0, stream, x, xb);
    hipLaunchKernelGGL(k_wbf, dim3(CPAD), dim3(256), 0, stream, c1w, wbf);
    hipLaunchKernelGGL(k_conv1m, dim3(BATCH, 9, 9), dim3(256), 0, stream,
                       xb, wbf, ing, cb1w, cb1b, cb2w, cb2b, tb2, h);
    hipLaunchKernelGGL(k_wlin, dim3(NPH), dim3(256), 0, stream, linw, wlb);
    hipLaunchKernelGGL(k_maskm, dim3(MP / 128, NPH / 128), dim3(256), 0, stream,
                       h, wlb, linb, fcg, (unsigned*)tb2);
    hipLaunchKernelGGL(k_wdt, dim3(KPC), dim3(256), 0, stream, ctw, wdb);
    hipLaunchKernelGGL(k_convtm, dim3(256, 2), dim3(256), 0, stream,
                       tb2, wdb, out);
}

// Round 6
// 512.193 us; speedup vs baseline: 14.8798x; 1.0479x over previous
//
#include <hip/hip_runtime.h>
#include <cstddef>
#include <cstdint>

#define TIME_N 262144
#define BATCH  32
#define KW     1024
#define ST     256
#define CUTN   513
#define TCN    1026
#define FN     1029   // frames
#define FPAD   1152
#define CPAD   1152
#define XLEN   (FPAD * ST + KW)   // 295936 bf16 per batch row
#define XBLK   (XLEN / 256)       // 1156

// mask GEMM dims
#define MROWS  (BATCH * FN)   // 32928
#define MP     33024          // 258*128
#define KPH    544            // 513 -> 17*32
#define NPH    640            // 513 -> 5*128
// convT GEMM dims / flat bf16 t layout (re/im PAIR-INTERLEAVED: col 2y=re_y, 2y+1=im_y)
#define TBP    1032           // flat bf16 t row stride (16B-aligned)
#define FLATB  (FN * TBP)     // per-batch flat size
#define KPC    4128           // 4*1032, 129*32

// k_prep block ranges
#define PB_XPAD  (XBLK * BATCH)            // 36992
#define PB_WBF   (PB_XPAD + CPAD)          // +1152
#define PB_WLIN  (PB_WBF + NPH)            // +640
#define PB_TOTAL (PB_WLIN + KPC)           // +4128

typedef __bf16 bf16x8 __attribute__((ext_vector_type(8)));
typedef float floatx4 __attribute__((ext_vector_type(4)));

__device__ __forceinline__ unsigned short f2bf(float f) {
    union { float f; unsigned u; } v; v.f = f;
    unsigned r = (v.u + 0x7fffu + ((v.u >> 16) & 1u)) >> 16;
    return (unsigned short)r;
}
__device__ __forceinline__ float bf2f(unsigned short s) {
    union { unsigned u; float f; } v; v.u = ((unsigned)s) << 16;
    return v.f;
}
// interleaved column n -> original channel index
__device__ __forceinline__ int permch(int n) {
    return (n & 1) ? (CUTN + (n >> 1)) : (n >> 1);
}

__device__ __forceinline__ void load_lds16(const void* g, void* l) {
    __builtin_amdgcn_global_load_lds(
        (const __attribute__((address_space(1))) void*)g,
        (__attribute__((address_space(3))) void*)l, 16, 0, 0);
}

// ---------------------------------------------------------------------------
// k_prep: all input-conversion work in ONE launch, split by blockIdx range.
//   [0, PB_XPAD)   : zero-padded bf16 copy of x
//   [.., PB_WBF)   : conv1 weights bf16, pair-interleaved rows, [1152][1024]
//   [.., PB_WLIN)  : lin_w bf16 padded [640][544]
//   [.., PB_TOTAL) : differenced convT weights bf16 [256][4128], interleaved
// ---------------------------------------------------------------------------
__global__ __launch_bounds__(256) void k_prep(
    const float* __restrict__ x, const float* __restrict__ c1w,
    const float* __restrict__ lw, const float* __restrict__ wct,
    unsigned short* __restrict__ xb, unsigned short* __restrict__ wbf,
    unsigned short* __restrict__ wlb, unsigned short* __restrict__ wdb)
{
    const int bid = blockIdx.x;
    if (bid < PB_XPAD) {
        const int b = bid / XBLK;
        const int p = (bid - b * XBLK) * 256 + threadIdx.x;
        const int g = p - KW;
        float v = (g >= 0 && g < TIME_N) ? x[(size_t)b * TIME_N + g] : 0.0f;
        xb[(size_t)b * XLEN + p] = f2bf(v);
    } else if (bid < PB_WBF) {
        const int n = bid - PB_XPAD;              // 0..1151 interleaved row
        const int ch = (n < TCN) ? permch(n) : 0;
        for (int k = threadIdx.x; k < KW; k += 256) {
            float v = (n < TCN) ? c1w[(size_t)ch * KW + k] : 0.0f;
            wbf[(size_t)n * KW + k] = f2bf(v);
        }
    } else if (bid < PB_WLIN) {
        const int n = bid - PB_WBF;               // 0..639
        for (int k = threadIdx.x; k < KPH; k += 256) {
            float v = (n < CUTN && k < CUTN) ? lw[(size_t)n * CUTN + k] : 0.0f;
            wlb[(size_t)n * KPH + k] = f2bf(v);
        }
    } else {
        const int k = bid - PB_WLIN;              // 0..4127
        const int r = threadIdx.x;                // 0..255
        const int j = k / TBP;
        const int n = k - j * TBP;
        float v = 0.0f;
        if (n < TCN) {
            const int ch = permch(n);
            const int widx = (3 - j) * 256 + r;
            v = wct[(size_t)(2 * ch) * KW + widx] -
                wct[(size_t)(2 * ch + 1) * KW + widx];
        }
        wdb[(size_t)r * KPC + k] = f2bf(v);
    }
}

// ---------------------------------------------------------------------------
// Kernel 1 (MFMA): conv1 bf16 GEMM; epilogue: tanh(gamma*.) -> pair-
// interleaved tb2 + h=MLP(re,im). Both-lane scheme: frames handled in
// (r, r+1) pairs; even lane owns frame r, odd lane frame r+1 — all lanes
// store + compute MLP (no divergent idle half).
// ---------------------------------------------------------------------------
__global__ __launch_bounds__(256) void k_conv1m(
    const unsigned short* __restrict__ xb, const unsigned short* __restrict__ wb,
    const float* __restrict__ gamma,
    const float* __restrict__ c1w, const float* __restrict__ c1b,
    const float* __restrict__ c2w, const float* __restrict__ c2b,
    unsigned short* __restrict__ tb2, unsigned short* __restrict__ h)
{
    __shared__ __align__(16) unsigned short As[128 * 32];
    __shared__ __align__(16) unsigned short Bs[128 * 32];

    const int b = blockIdx.x, fb = blockIdx.y, cb = blockIdx.z;
    const int f0 = fb * 128, c0 = cb * 128;
    const int tid = threadIdx.x;

    const int s0 = tid, s1 = tid + 256;
    const int ar0 = s0 >> 2, aq0 = s0 & 3;
    const int ar1 = s1 >> 2, aq1 = s1 & 3;
    const unsigned short* xrow = xb + (size_t)b * XLEN;
    const unsigned short* ga0 = xrow + (size_t)(f0 + ar0) * ST + aq0 * 8;
    const unsigned short* ga1 = xrow + (size_t)(f0 + ar1) * ST + aq1 * 8;
    const unsigned short* gb0 = wb + (size_t)(c0 + ar0) * KW + aq0 * 8;
    const unsigned short* gb1 = wb + (size_t)(c0 + ar1) * KW + aq1 * 8;
    unsigned short* la0 = &As[s0 * 8];
    unsigned short* la1 = &As[s1 * 8];
    unsigned short* lb0 = &Bs[s0 * 8];
    unsigned short* lb1 = &Bs[s1 * 8];

    const int wave = tid >> 6, lane = tid & 63;
    const int lm = lane & 15, lq = lane >> 4;
    const int mw = (wave & 1) * 64, nw = (wave >> 1) * 64;
    const unsigned short* Ap = &As[(mw + lm) * 32 + lq * 8];
    const unsigned short* Bp = &Bs[(nw + lm) * 32 + lq * 8];

    floatx4 acc[4][4];
#pragma unroll
    for (int i = 0; i < 4; ++i)
#pragma unroll
        for (int j = 0; j < 4; ++j) acc[i][j] = (floatx4)0.0f;

    for (int ks = 0; ks < KW / 32; ++ks) {
        load_lds16(ga0, la0);
        load_lds16(ga1, la1);
        load_lds16(gb0, lb0);
        load_lds16(gb1, lb1);
        ga0 += 32; ga1 += 32; gb0 += 32; gb1 += 32;
        __syncthreads();

        bf16x8 afr[4], bfr[4];
#pragma unroll
        for (int mt = 0; mt < 4; ++mt) afr[mt] = *(const bf16x8*)(Ap + mt * 16 * 32);
#pragma unroll
        for (int nt = 0; nt < 4; ++nt) bfr[nt] = *(const bf16x8*)(Bp + nt * 16 * 32);
#pragma unroll
        for (int mt = 0; mt < 4; ++mt)
#pragma unroll
            for (int nt = 0; nt < 4; ++nt)
                acc[mt][nt] = __builtin_amdgcn_mfma_f32_16x16x32_bf16(
                    afr[mt], bfr[nt], acc[mt][nt], 0, 0, 0);
        __syncthreads();
    }

    // epilogue
    float w1[16], b1[8], w2[8];
#pragma unroll
    for (int o = 0; o < 8; ++o) {
        w1[2 * o]     = c1w[2 * o];
        w1[2 * o + 1] = c1w[2 * o + 1];
        b1[o] = c1b[o];
        w2[o] = c2w[o];
    }
    const float b2v = c2b[0];

    unsigned short* tbb = tb2 + (size_t)b * FLATB;
    const bool evenlane = ((lane & 1) == 0);
#pragma unroll
    for (int nt = 0; nt < 4; ++nt) {
        const int n = c0 + nw + nt * 16 + lm;
        const bool valid_c = (n < TCN);
        const float gv = valid_c ? gamma[permch(n)] : 0.0f;
        const int nbase = n & ~1;
        const int ybase = n >> 1;
        const bool store_c = (nbase < TBP);
#pragma unroll
        for (int mt = 0; mt < 4; ++mt) {
#pragma unroll
            for (int rp = 0; rp < 2; ++rp) {
                const int ra = rp * 2;
                const int fa = f0 + mw + mt * 16 + lq * 4 + ra;
                const float ua = acc[mt][nt][ra] * gv;
                const float ub = acc[mt][nt][ra + 1] * gv;
                const float ta  = 2.0f / (1.0f + __expf(-2.0f * ua)) - 1.0f;
                const float tbv = 2.0f / (1.0f + __expf(-2.0f * ub)) - 1.0f;
                const float sa = __shfl_xor(ta, 1);
                const float sb = __shfl_xor(tbv, 1);
                // even lane owns frame fa with (re=ta, im=sa);
                // odd lane owns frame fa+1 with (re=sb, im=tbv)
                const int  fme = evenlane ? fa : (fa + 1);
                const float re = evenlane ? ta : sb;
                const float im = evenlane ? sa : tbv;
                if (fme < FN) {
                    if (store_c) {
                        const unsigned pr = (unsigned)f2bf(re) |
                                            ((unsigned)f2bf(im) << 16);
                        *(unsigned*)&tbb[(size_t)fme * TBP + nbase] = pr;
                    }
                    if (valid_c) {
                        float a2 = b2v;
#pragma unroll
                        for (int o = 0; o < 8; ++o) {
                            const float a1 = fmaxf(
                                re * w1[2 * o] + im * w1[2 * o + 1] + b1[o], 0.0f);
                            a2 += a1 * w2[o];
                        }
                        h[((size_t)b * FN + fme) * KPH + ybase] =
                            f2bf(fmaxf(a2, 0.0f));
                    }
                }
            }
        }
    }
}

// ---------------------------------------------------------------------------
// k_maskm (MFMA): hh = H * Wlin^T; mask = sigmoid(2*(hh+b)*g);
// RMW: one aligned uint per (m,y) scales the (re,im) pair in tb2.
// ---------------------------------------------------------------------------
__global__ __launch_bounds__(256) void k_maskm(
    const unsigned short* __restrict__ h, const unsigned short* __restrict__ wlb,
    const float* __restrict__ linb, const float* __restrict__ fcg,
    unsigned* __restrict__ tbu)
{
    __shared__ __align__(16) unsigned short As[128 * 32];
    __shared__ __align__(16) unsigned short Bs[128 * 32];

    const int m0 = blockIdx.x * 128, n0 = blockIdx.y * 128;
    const int tid = threadIdx.x;

    const int s0 = tid, s1 = tid + 256;
    const int ar0 = s0 >> 2, aq0 = s0 & 3;
    const int ar1 = s1 >> 2, aq1 = s1 & 3;
    const unsigned short* ga0 = h + (size_t)(m0 + ar0) * KPH + aq0 * 8;
    const unsigned short* ga1 = h + (size_t)(m0 + ar1) * KPH + aq1 * 8;
    const unsigned short* gb0 = wlb + (size_t)(n0 + ar0) * KPH + aq0 * 8;
    const unsigned short* gb1 = wlb + (size_t)(n0 + ar1) * KPH + aq1 * 8;
    unsigned short* la0 = &As[s0 * 8];
    unsigned short* la1 = &As[s1 * 8];
    unsigned short* lb0 = &Bs[s0 * 8];
    unsigned short* lb1 = &Bs[s1 * 8];

    const int wave = tid >> 6, lane = tid & 63;
    const int lm = lane & 15, lq = lane >> 4;
    const int mw = (wave & 1) * 64, nw = (wave >> 1) * 64;
    const unsigned short* Ap = &As[(mw + lm) * 32 + lq * 8];
    const unsigned short* Bp = &Bs[(nw + lm) * 32 + lq * 8];

    floatx4 acc[4][4];
#pragma unroll
    for (int i = 0; i < 4; ++i)
#pragma unroll
        for (int j = 0; j < 4; ++j) acc[i][j] = (floatx4)0.0f;

    for (int ks = 0; ks < KPH / 32; ++ks) {
        load_lds16(ga0, la0);
        load_lds16(ga1, la1);
        load_lds16(gb0, lb0);
        load_lds16(gb1, lb1);
        ga0 += 32; ga1 += 32; gb0 += 32; gb1 += 32;
        __syncthreads();

        bf16x8 afr[4], bfr[4];
#pragma unroll
        for (int mt = 0; mt < 4; ++mt) afr[mt] = *(const bf16x8*)(Ap + mt * 16 * 32);
#pragma unroll
        for (int nt = 0; nt < 4; ++nt) bfr[nt] = *(const bf16x8*)(Bp + nt * 16 * 32);
#pragma unroll
        for (int mt = 0; mt < 4; ++mt)
#pragma unroll
            for (int nt = 0; nt < 4; ++nt)
                acc[mt][nt] = __builtin_amdgcn_mfma_f32_16x16x32_bf16(
                    afr[mt], bfr[nt], acc[mt][nt], 0, 0, 0);
        __syncthreads();
    }

#pragma unroll
    for (int nt = 0; nt < 4; ++nt) {
        const int y = n0 + nw + nt * 16 + lm;
        if (y < CUTN) {
            const float lb = linb[y];
            const float gv = fcg[y];
#pragma unroll
            for (int mt = 0; mt < 4; ++mt) {
#pragma unroll
                for (int r = 0; r < 4; ++r) {
                    const int m = m0 + mw + mt * 16 + lq * 4 + r;
                    if (m < MROWS) {
                        const float v = (acc[mt][nt][r] + lb) * gv;
                        const float msk = 1.0f / (1.0f + __expf(-2.0f * v));
                        unsigned* p = tbu + (size_t)m * (TBP / 2) + y;
                        const unsigned u = *p;
                        const float re = bf2f((unsigned short)(u & 0xffffu)) * msk;
                        const float im = bf2f((unsigned short)(u >> 16)) * msk;
                        *p = (unsigned)f2bf(re) | ((unsigned)f2bf(im) << 16);
                    }
                }
            }
        }
    }
}

// ---------------------------------------------------------------------------
// k_convtm (MFMA): d[m][r] = A(tb2 windows) * Wd^T, fused sigmoid softmax.
// ---------------------------------------------------------------------------
__global__ __launch_bounds__(256) void k_convtm(
    const unsigned short* __restrict__ tb2, const unsigned short* __restrict__ wdb,
    float* __restrict__ out)
{
    __shared__ __align__(16) unsigned short As[128 * 32];
    __shared__ __align__(16) unsigned short Bs[128 * 32];

    const int m0 = blockIdx.x * 128, n0 = blockIdx.y * 128;
    const int b   = m0 >> 10;
    const int ml0 = m0 & 1023;
    const int tid = threadIdx.x;

    const int s0 = tid, s1 = tid + 256;
    const int ar0 = s0 >> 2, aq0 = s0 & 3;
    const int ar1 = s1 >> 2, aq1 = s1 & 3;
    const unsigned short* tbb = tb2 + (size_t)b * FLATB;
    const unsigned short* ga0 = tbb + (size_t)(ml0 + ar0 + 1) * TBP + aq0 * 8;
    const unsigned short* ga1 = tbb + (size_t)(ml0 + ar1 + 1) * TBP + aq1 * 8;
    const unsigned short* gb0 = wdb + (size_t)(n0 + ar0) * KPC + aq0 * 8;
    const unsigned short* gb1 = wdb + (size_t)(n0 + ar1) * KPC + aq1 * 8;
    unsigned short* la0 = &As[s0 * 8];
    unsigned short* la1 = &As[s1 * 8];
    unsigned short* lb0 = &Bs[s0 * 8];
    unsigned short* lb1 = &Bs[s1 * 8];

    const int wave = tid >> 6, lane = tid & 63;
    const int lm = lane & 15, lq = lane >> 4;
    const int mw = (wave & 1) * 64, nw = (wave >> 1) * 64;
    const unsigned short* Ap = &As[(mw + lm) * 32 + lq * 8];
    const unsigned short* Bp = &Bs[(nw + lm) * 32 + lq * 8];

    floatx4 acc[4][4];
#pragma unroll
    for (int i = 0; i < 4; ++i)
#pragma unroll
        for (int j = 0; j < 4; ++j) acc[i][j] = (floatx4)0.0f;

    for (int ks = 0; ks < KPC / 32; ++ks) {
        load_lds16(ga0, la0);
        load_lds16(ga1, la1);
        load_lds16(gb0, lb0);
        load_lds16(gb1, lb1);
        ga0 += 32; ga1 += 32; gb0 += 32; gb1 += 32;
        __syncthreads();

        bf16x8 afr[4], bfr[4];
#pragma unroll
        for (int mt = 0; mt < 4; ++mt) afr[mt] = *(const bf16x8*)(Ap + mt * 16 * 32);
#pragma unroll
        for (int nt = 0; nt < 4; ++nt) bfr[nt] = *(const bf16x8*)(Bp + nt * 16 * 32);
#pragma unroll
        for (int mt = 0; mt < 4; ++mt)
#pragma unroll
            for (int nt = 0; nt < 4; ++nt)
                acc[mt][nt] = __builtin_amdgcn_mfma_f32_16x16x32_bf16(
                    afr[mt], bfr[nt], acc[mt][nt], 0, 0, 0);
        __syncthreads();
    }

    float* ob = out + (size_t)b * 2 * TIME_N;
#pragma unroll
    for (int nt = 0; nt < 4; ++nt) {
        const int n = n0 + nw + nt * 16 + lm;
#pragma unroll
        for (int mt = 0; mt < 4; ++mt) {
#pragma unroll
            for (int r = 0; r < 4; ++r) {
                const int m = ml0 + mw + mt * 16 + lq * 4 + r;
                const float d = acc[mt][nt][r];
                const float p0 = 1.0f / (1.0f + __expf(-d));
                const int tau = m * 256 + n;
                ob[tau]          = p0;
                ob[TIME_N + tau] = 1.0f - p0;
            }
        }
    }
}

extern "C" void kernel_launch(void* const* d_in, const int* in_sizes, int n_in,
                              void* d_out, int out_size, void* d_ws, size_t ws_size,
                              hipStream_t stream)
{
    const float* x    = (const float*)d_in[0];
    const float* c1w  = (const float*)d_in[1];
    const float* ing  = (const float*)d_in[2];
    const float* cb1w = (const float*)d_in[3];
    const float* cb1b = (const float*)d_in[4];
    const float* cb2w = (const float*)d_in[5];
    const float* cb2b = (const float*)d_in[6];
    const float* linw = (const float*)d_in[7];
    const float* linb = (const float*)d_in[8];
    const float* fcg  = (const float*)d_in[9];
    const float* ctw  = (const float*)d_in[10];
    float* out = (float*)d_out;

    // ---- workspace layout (all bf16) ----
    unsigned short* tb2 = (unsigned short*)d_ws;           // 32*1029*1032
    unsigned short* h   = tb2 + (size_t)BATCH * FLATB;     // 33024*544
    unsigned short* wlb = h + (size_t)MP * KPH;            // 640*544
    unsigned short* xb  = wlb + (size_t)NPH * KPH;         // 32*XLEN
    unsigned short* wbf = xb + (size_t)BATCH * XLEN;       // 1152*1024
    unsigned short* wdb = wbf + (size_t)CPAD * KW;         // 256*4128

    hipLaunchKernelGGL(k_prep, dim3(PB_TOTAL), dim3(256), 0, stream,
                       x, c1w, linw, ctw, xb, wbf, wlb, wdb);
    hipLaunchKernelGGL(k_conv1m, dim3(BATCH, 9, 9), dim3(256), 0, stream,
                       xb, wbf, ing, cb1w, cb1b, cb2w, cb2b, tb2, h);
    hipLaunchKernelGGL(k_maskm, dim3(MP / 128, NPH / 128), dim3(256), 0, stream,
                       h, wlb, linb, fcg, (unsigned*)tb2);
    hipLaunchKernelGGL(k_convtm, dim3(256, 2), dim3(256), 0, stream,
                       tb2, wdb, out);
}